// Round 1
// baseline (886.179 us; speedup 1.0000x reference)
//
#include <hip/hip_runtime.h>
#include <hip/hip_bf16.h>

// BMMGroupedGEMM: out[e,m,n] = sum_k x[e,m,k] * w[e,n,k], rows m >= m_sizes[e] zeroed.
// E=8, MAX_M=2048, K=2048, N=8192. fp32 in/out; bf16 MFMA inside (error << 0.105 threshold).

#define NE   8
#define MAXM 2048
#define KD   2048
#define ND   8192
#define BM   128
#define BN   128
#define BK   32
#define TM   (MAXM/BM)   // 16
#define TN   (ND/BN)     // 64
#define NT   (KD/BK)     // 64
#define LSTR 40          // LDS row stride in bf16 elems: 80B, 16B-aligned, bank-friendly

typedef __attribute__((ext_vector_type(8))) short   short8;
typedef __attribute__((ext_vector_type(4))) float   f32x4;
typedef __attribute__((ext_vector_type(4))) unsigned short us4;

__device__ __forceinline__ unsigned short f2bf(float f) {
    union { float f; unsigned u; } v; v.f = f;
    unsigned u = v.u;
    return (unsigned short)((u + 0x7FFFu + ((u >> 16) & 1u)) >> 16);  // RNE
}

__global__ __launch_bounds__(256, 2) void ggemm_kernel(
    const float* __restrict__ x,   // [E, MAXM, KD]
    const float* __restrict__ w,   // [E, ND, KD]
    const int*   __restrict__ ms,  // [E]
    float*       __restrict__ out) // [E, MAXM, ND]
{
    // XCD-aware bijective swizzle (nwg = 8192, divisible by 8)
    int nwg  = gridDim.x;
    int orig = blockIdx.x;
    int cpx  = nwg >> 3;
    int bid  = (orig & 7) * cpx + (orig >> 3);

    int e   = bid / (TM * TN);
    int rem = bid % (TM * TN);
    int br  = rem % TM;          // br fastest: 16 consecutive blocks share the B panel
    int bc  = rem / TM;

    int m_size = ms[e];
    int row0 = br * BM, col0 = bc * BN;
    float* outE = out + (size_t)e * MAXM * ND;
    int tid = threadIdx.x;

    if (row0 >= m_size) {
        // whole tile is masked: zero-fill 128x128 fp32 (d_out is poisoned, must write)
        f32x4 z = (f32x4){0.f, 0.f, 0.f, 0.f};
        #pragma unroll
        for (int j = 0; j < 16; ++j) {
            int idx = tid + j * 256;          // float4 index in tile (32 per row)
            int rr = idx >> 5, cc = (idx & 31) << 2;
            *(f32x4*)(outE + (size_t)(row0 + rr) * ND + col0 + cc) = z;
        }
        return;
    }

    const float* xE = x + ((size_t)e * MAXM + row0) * KD;
    const float* wE = w + ((size_t)e * ND   + col0) * KD;

    __shared__ unsigned short As[2][BM][LSTR];
    __shared__ unsigned short Bs[2][BN][LSTR];

    // staging: tile is 128 rows x 32 f32 = 1024 float4; thread t handles
    // float4 #(t + j*256) -> row = f>>3 (8 float4/row), c4 = f&7.
    // per-instruction: 8 consecutive lanes read 128B contiguous (coalesced).
    int sr  = tid >> 3;        // base row (j adds 32)
    int sc4 = tid & 7;         // float4 column (0..7)

    int wid = tid >> 6, lane = tid & 63;
    int wr = wid >> 1, wc = wid & 1;      // 2x2 wave grid, each wave 64x64 out
    int lr = lane & 15, kg = lane >> 4;   // fragment row / k-group

    f32x4 acc[4][4];
    #pragma unroll
    for (int m = 0; m < 4; ++m)
        #pragma unroll
        for (int n = 0; n < 4; ++n)
            acc[m][n] = (f32x4){0.f, 0.f, 0.f, 0.f};

    // prologue: stage k-tile 0 into buf 0
    {
        #pragma unroll
        for (int j = 0; j < 4; ++j) {
            int r0 = sr + j * 32;
            f32x4 av = *(const f32x4*)(xE + (size_t)r0 * KD + sc4 * 4);
            f32x4 bv = *(const f32x4*)(wE + (size_t)r0 * KD + sc4 * 4);
            us4 ah = (us4){f2bf(av[0]), f2bf(av[1]), f2bf(av[2]), f2bf(av[3])};
            us4 bh = (us4){f2bf(bv[0]), f2bf(bv[1]), f2bf(bv[2]), f2bf(bv[3])};
            *(us4*)&As[0][r0][sc4 * 4] = ah;
            *(us4*)&Bs[0][r0][sc4 * 4] = bh;
        }
    }
    __syncthreads();

    for (int t = 0; t < NT; ++t) {
        int cur = t & 1;
        f32x4 av[4], bv[4];
        bool pre = (t + 1 < NT);
        if (pre) {
            const float* xk = xE + (size_t)(t + 1) * BK;
            const float* wk = wE + (size_t)(t + 1) * BK;
            #pragma unroll
            for (int j = 0; j < 4; ++j) {
                int r0 = sr + j * 32;
                av[j] = *(const f32x4*)(xk + (size_t)r0 * KD + sc4 * 4);
                bv[j] = *(const f32x4*)(wk + (size_t)r0 * KD + sc4 * 4);
            }
        }

        // compute on buf[cur]
        short8 a[4], b[4];
        #pragma unroll
        for (int m = 0; m < 4; ++m)
            a[m] = *(const short8*)&As[cur][wr * 64 + m * 16 + lr][kg * 8];
        #pragma unroll
        for (int n = 0; n < 4; ++n)
            b[n] = *(const short8*)&Bs[cur][wc * 64 + n * 16 + lr][kg * 8];
        #pragma unroll
        for (int m = 0; m < 4; ++m)
            #pragma unroll
            for (int n = 0; n < 4; ++n)
                acc[m][n] = __builtin_amdgcn_mfma_f32_16x16x32_bf16(a[m], b[n], acc[m][n], 0, 0, 0);

        if (pre) {
            int nb = cur ^ 1;
            #pragma unroll
            for (int j = 0; j < 4; ++j) {
                int r0 = sr + j * 32;
                us4 ah = (us4){f2bf(av[j][0]), f2bf(av[j][1]), f2bf(av[j][2]), f2bf(av[j][3])};
                us4 bh = (us4){f2bf(bv[j][0]), f2bf(bv[j][1]), f2bf(bv[j][2]), f2bf(bv[j][3])};
                *(us4*)&As[nb][r0][sc4 * 4] = ah;
                *(us4*)&Bs[nb][r0][sc4 * 4] = bh;
            }
        }
        __syncthreads();
    }

    // epilogue: C/D layout (16x16x32): col = lane&15, row = (lane>>4)*4 + j
    #pragma unroll
    for (int m = 0; m < 4; ++m) {
        int rbase = row0 + wr * 64 + m * 16 + kg * 4;
        #pragma unroll
        for (int n = 0; n < 4; ++n) {
            int gc = col0 + wc * 64 + n * 16 + lr;
            #pragma unroll
            for (int j = 0; j < 4; ++j) {
                int gr = rbase + j;
                float v = (gr < m_size) ? acc[m][n][j] : 0.f;
                outE[(size_t)gr * ND + gc] = v;
            }
        }
    }
}

extern "C" void kernel_launch(void* const* d_in, const int* in_sizes, int n_in,
                              void* d_out, int out_size, void* d_ws, size_t ws_size,
                              hipStream_t stream) {
    const float* x  = (const float*)d_in[0];
    const float* w  = (const float*)d_in[1];
    const int*   ms = (const int*)d_in[2];
    float* out = (float*)d_out;

    dim3 grid(NE * TM * TN);   // 8192 blocks
    dim3 block(256);
    ggemm_kernel<<<grid, block, 0, stream>>>(x, w, ms, out);
}

// Round 2
// 738.857 us; speedup vs baseline: 1.1994x; 1.1994x over previous
//
#include <hip/hip_runtime.h>
#include <hip/hip_bf16.h>

// BMMGroupedGEMM: out[e,m,n] = sum_k x[e,m,k] * w[e,n,k], rows m >= m_sizes[e] zeroed.
// E=8, MAX_M=2048, K=2048, N=8192. fp32 in/out.
// Round 2: two-pass. Pass 1: fp32 -> bf16 into d_ws. Pass 2: m97-structure bf16 GEMM
// (128x128 tile, BK=32, global_load_lds width=16, LDS double-buffer, 1 barrier/K-step).
// Fallback to round-1 fused kernel if d_ws too small.

#define NE   8
#define MAXM 2048
#define KD   2048
#define ND   8192
#define BM   128
#define BN   128
#define BK   32
#define TM   (MAXM/BM)   // 16
#define TN   (ND/BN)     // 64
#define NT   (KD/BK)     // 64

typedef __attribute__((ext_vector_type(8))) short          short8;
typedef __attribute__((ext_vector_type(8))) unsigned short us8;
typedef __attribute__((ext_vector_type(4))) float          f32x4;
typedef __attribute__((ext_vector_type(4))) unsigned short us4;

__device__ __forceinline__ unsigned short f2bf(float f) {
    union { float f; unsigned u; } v; v.f = f;
    unsigned u = v.u;
    return (unsigned short)((u + 0x7FFFu + ((u >> 16) & 1u)) >> 16);  // RNE
}

__device__ __forceinline__ void gload16(const void* g, void* l) {
    __builtin_amdgcn_global_load_lds(
        (const __attribute__((address_space(1))) void*)g,
        (__attribute__((address_space(3))) void*)l, 16, 0, 0);
}

// ---------------- Pass 1: fp32 -> bf16 conversion (memory-bound) ----------------
__global__ __launch_bounds__(256) void cvt_kernel(const float* __restrict__ src,
                                                  unsigned short* __restrict__ dst,
                                                  int n8) {
    int i = blockIdx.x * blockDim.x + threadIdx.x;
    int stride = gridDim.x * blockDim.x;
    for (; i < n8; i += stride) {
        const f32x4* s = (const f32x4*)(src + (size_t)i * 8);
        f32x4 a = s[0], b = s[1];
        us8 v = (us8){f2bf(a[0]), f2bf(a[1]), f2bf(a[2]), f2bf(a[3]),
                      f2bf(b[0]), f2bf(b[1]), f2bf(b[2]), f2bf(b[3])};
        *(us8*)(dst + (size_t)i * 8) = v;
    }
}

// ---------------- Pass 2: bf16 GEMM, m97 structure ----------------
__global__ __launch_bounds__(256, 2) void ggemm_bf16(
    const unsigned short* __restrict__ xb,  // [E][MAXM][KD] bf16
    const unsigned short* __restrict__ wb,  // [E][ND][KD]  bf16
    const int*   __restrict__ ms,
    float*       __restrict__ out)          // [E][MAXM][ND] fp32
{
    // XCD-aware bijective swizzle: orig%8 -> XCD chunk (gridDim = 8192, %8==0)
    int orig = blockIdx.x;
    int cpx  = gridDim.x >> 3;
    int bid  = (orig & 7) * cpx + (orig >> 3);

    int e = bid >> 10;              // 1024 tiles per expert
    int r = bid & 1023;
    // 16x8 super-tiles: s(8) x br(16) x c(8) -> 32 consecutive bids touch
    // 4 A-panels + 8 B-panels (~6 MB bf16) for L2 locality.
    int s  = r >> 7;
    int br = (r >> 3) & 15;
    int bc = (s << 3) | (r & 7);

    int m_size = ms[e];
    int row0 = br * BM, col0 = bc * BN;
    float* outE = out + (size_t)e * MAXM * ND;
    int tid = threadIdx.x;

    if (row0 >= m_size) {
        f32x4 z = (f32x4){0.f, 0.f, 0.f, 0.f};
        #pragma unroll
        for (int j = 0; j < 16; ++j) {
            int idx = tid + j * 256;
            int rr = idx >> 5, cc = (idx & 31) << 2;
            *(f32x4*)(outE + (size_t)(row0 + rr) * ND + col0 + cc) = z;
        }
        return;
    }

    const unsigned short* xE = xb + ((size_t)e * MAXM + row0) * KD;
    const unsigned short* wE = wb + ((size_t)e * ND   + col0) * KD;

    __shared__ unsigned short As[2][BM * BK];   // 8 KB each buf, linear [row][k]
    __shared__ unsigned short Bs[2][BN * BK];

    int wid = tid >> 6, lane = tid & 63;
    int wr = wid >> 1, wc = wid & 1;        // 2x2 wave grid, 64x64 out each
    int lr = lane & 15, kg = lane >> 4;
    int crow = lane >> 2;                   // row within 16-row chunk
    int ck8  = lane & 3;                    // 8-elem K group within BK=32

    f32x4 acc[4][4];
    #pragma unroll
    for (int m = 0; m < 4; ++m)
        #pragma unroll
        for (int n = 0; n < 4; ++n)
            acc[m][n] = (f32x4){0.f, 0.f, 0.f, 0.f};

    // stage one K-tile (A+B) into buffer cur: 8 chunks each of 1024B,
    // wave w writes chunks {w, w+4}; LDS dest is wave-uniform, src per-lane.
    auto stage = [&](int cur, int kt) {
        #pragma unroll
        for (int i = 0; i < 2; ++i) {
            int c = wid + i * 4;
            const unsigned short* sa = xE + (size_t)(c * 16 + crow) * KD + kt * BK + ck8 * 8;
            gload16(sa, (char*)&As[cur][0] + c * 1024);
        }
        #pragma unroll
        for (int i = 0; i < 2; ++i) {
            int c = wid + i * 4;
            const unsigned short* sb = wE + (size_t)(c * 16 + crow) * KD + kt * BK + ck8 * 8;
            gload16(sb, (char*)&Bs[cur][0] + c * 1024);
        }
    };

    stage(0, 0);
    __syncthreads();

    for (int t = 0; t < NT; ++t) {
        int cur = t & 1;
        if (t + 1 < NT) stage(cur ^ 1, t + 1);

        short8 a[4], b[4];
        #pragma unroll
        for (int m = 0; m < 4; ++m)
            a[m] = *(const short8*)&As[cur][(wr * 64 + m * 16 + lr) * BK + kg * 8];
        #pragma unroll
        for (int n = 0; n < 4; ++n)
            b[n] = *(const short8*)&Bs[cur][(wc * 64 + n * 16 + lr) * BK + kg * 8];
        #pragma unroll
        for (int m = 0; m < 4; ++m)
            #pragma unroll
            for (int n = 0; n < 4; ++n)
                acc[m][n] = __builtin_amdgcn_mfma_f32_16x16x32_bf16(a[m], b[n], acc[m][n], 0, 0, 0);

        __syncthreads();  // drains vmcnt(0): next buffer staged, this buffer free
    }

    // epilogue: C/D layout (16x16x32): col = lane&15, row = (lane>>4)*4 + j
    #pragma unroll
    for (int m = 0; m < 4; ++m) {
        int rbase = row0 + wr * 64 + m * 16 + kg * 4;
        #pragma unroll
        for (int n = 0; n < 4; ++n) {
            int gc = col0 + wc * 64 + n * 16 + lr;
            #pragma unroll
            for (int j = 0; j < 4; ++j) {
                int gr = rbase + j;
                float v = (gr < m_size) ? acc[m][n][j] : 0.f;
                outE[(size_t)gr * ND + gc] = v;
            }
        }
    }
}

// ---------------- Fallback: round-1 fused kernel (proven 886 us) ----------------
#define LSTR 40
__global__ __launch_bounds__(256, 2) void ggemm_fused(
    const float* __restrict__ x, const float* __restrict__ w,
    const int* __restrict__ ms, float* __restrict__ out)
{
    int nwg  = gridDim.x;
    int orig = blockIdx.x;
    int cpx  = nwg >> 3;
    int bid  = (orig & 7) * cpx + (orig >> 3);
    int e   = bid / (TM * TN);
    int rem = bid % (TM * TN);
    int br  = rem % TM;
    int bc  = rem / TM;
    int m_size = ms[e];
    int row0 = br * BM, col0 = bc * BN;
    float* outE = out + (size_t)e * MAXM * ND;
    int tid = threadIdx.x;

    if (row0 >= m_size) {
        f32x4 z = (f32x4){0.f, 0.f, 0.f, 0.f};
        #pragma unroll
        for (int j = 0; j < 16; ++j) {
            int idx = tid + j * 256;
            int rr = idx >> 5, cc = (idx & 31) << 2;
            *(f32x4*)(outE + (size_t)(row0 + rr) * ND + col0 + cc) = z;
        }
        return;
    }

    const float* xE = x + ((size_t)e * MAXM + row0) * KD;
    const float* wE = w + ((size_t)e * ND   + col0) * KD;

    __shared__ unsigned short As[2][BM][LSTR];
    __shared__ unsigned short Bs[2][BN][LSTR];

    int sr  = tid >> 3;
    int sc4 = tid & 7;
    int wid = tid >> 6, lane = tid & 63;
    int wr = wid >> 1, wc = wid & 1;
    int lr = lane & 15, kg = lane >> 4;

    f32x4 acc[4][4];
    #pragma unroll
    for (int m = 0; m < 4; ++m)
        #pragma unroll
        for (int n = 0; n < 4; ++n)
            acc[m][n] = (f32x4){0.f, 0.f, 0.f, 0.f};

    {
        #pragma unroll
        for (int j = 0; j < 4; ++j) {
            int r0 = sr + j * 32;
            f32x4 av = *(const f32x4*)(xE + (size_t)r0 * KD + sc4 * 4);
            f32x4 bv = *(const f32x4*)(wE + (size_t)r0 * KD + sc4 * 4);
            us4 ah = (us4){f2bf(av[0]), f2bf(av[1]), f2bf(av[2]), f2bf(av[3])};
            us4 bh = (us4){f2bf(bv[0]), f2bf(bv[1]), f2bf(bv[2]), f2bf(bv[3])};
            *(us4*)&As[0][r0][sc4 * 4] = ah;
            *(us4*)&Bs[0][r0][sc4 * 4] = bh;
        }
    }
    __syncthreads();

    for (int t = 0; t < NT; ++t) {
        int cur = t & 1;
        f32x4 av[4], bv[4];
        bool pre = (t + 1 < NT);
        if (pre) {
            const float* xk = xE + (size_t)(t + 1) * BK;
            const float* wk = wE + (size_t)(t + 1) * BK;
            #pragma unroll
            for (int j = 0; j < 4; ++j) {
                int r0 = sr + j * 32;
                av[j] = *(const f32x4*)(xk + (size_t)r0 * KD + sc4 * 4);
                bv[j] = *(const f32x4*)(wk + (size_t)r0 * KD + sc4 * 4);
            }
        }
        short8 a[4], b[4];
        #pragma unroll
        for (int m = 0; m < 4; ++m)
            a[m] = *(const short8*)&As[cur][wr * 64 + m * 16 + lr][kg * 8];
        #pragma unroll
        for (int n = 0; n < 4; ++n)
            b[n] = *(const short8*)&Bs[cur][wc * 64 + n * 16 + lr][kg * 8];
        #pragma unroll
        for (int m = 0; m < 4; ++m)
            #pragma unroll
            for (int n = 0; n < 4; ++n)
                acc[m][n] = __builtin_amdgcn_mfma_f32_16x16x32_bf16(a[m], b[n], acc[m][n], 0, 0, 0);

        if (pre) {
            int nb = cur ^ 1;
            #pragma unroll
            for (int j = 0; j < 4; ++j) {
                int r0 = sr + j * 32;
                us4 ah = (us4){f2bf(av[j][0]), f2bf(av[j][1]), f2bf(av[j][2]), f2bf(av[j][3])};
                us4 bh = (us4){f2bf(bv[j][0]), f2bf(bv[j][1]), f2bf(bv[j][2]), f2bf(bv[j][3])};
                *(us4*)&As[nb][r0][sc4 * 4] = ah;
                *(us4*)&Bs[nb][r0][sc4 * 4] = bh;
            }
        }
        __syncthreads();
    }

    #pragma unroll
    for (int m = 0; m < 4; ++m) {
        int rbase = row0 + wr * 64 + m * 16 + kg * 4;
        #pragma unroll
        for (int n = 0; n < 4; ++n) {
            int gc = col0 + wc * 64 + n * 16 + lr;
            #pragma unroll
            for (int j = 0; j < 4; ++j) {
                int gr = rbase + j;
                float v = (gr < m_size) ? acc[m][n][j] : 0.f;
                outE[(size_t)gr * ND + gc] = v;
            }
        }
    }
}

extern "C" void kernel_launch(void* const* d_in, const int* in_sizes, int n_in,
                              void* d_out, int out_size, void* d_ws, size_t ws_size,
                              hipStream_t stream) {
    const float* x  = (const float*)d_in[0];
    const float* w  = (const float*)d_in[1];
    const int*   ms = (const int*)d_in[2];
    float* out = (float*)d_out;

    const size_t xElems = (size_t)NE * MAXM * KD;   // 33,554,432
    const size_t wElems = (size_t)NE * ND   * KD;   // 134,217,728
    const size_t need   = (xElems + wElems) * 2;    // 335,544,320 B

    if (ws_size >= need) {
        unsigned short* xb = (unsigned short*)d_ws;
        unsigned short* wb = xb + xElems;
        cvt_kernel<<<2048, 256, 0, stream>>>(x, xb, (int)(xElems / 8));
        cvt_kernel<<<2048, 256, 0, stream>>>(w, wb, (int)(wElems / 8));
        ggemm_bf16<<<dim3(NE * TM * TN), dim3(256), 0, stream>>>(xb, wb, ms, out);
    } else {
        ggemm_fused<<<dim3(NE * TM * TN), dim3(256), 0, stream>>>(x, w, ms, out);
    }
}

// Round 3
// 694.043 us; speedup vs baseline: 1.2768x; 1.0646x over previous
//
#include <hip/hip_runtime.h>
#include <hip/hip_bf16.h>

// BMMGroupedGEMM: out[e,m,n] = sum_k x[e,m,k] * w[e,n,k], rows m >= m_sizes[e] zeroed.
// E=8, MAX_M=2048, K=2048, N=8192. fp32 in/out.
// Round 3: pass 1 fp32->bf16 into d_ws (unchanged); pass 2 = 8-phase 256x256 schedule
// (T3+T4 counted vmcnt, T2 LDS swizzle via pre-swizzled global source, T5 setprio,
//  T1 XCD swizzle). K-half LDS ring, race ledger in comments.

#define NE   8
#define MAXM 2048
#define KD   2048
#define ND   8192

// 8-phase GEMM geometry
#define BM   256
#define BN   256
#define BK   64
#define NT   (KD/BK)     // 32
#define TMB  (MAXM/BM)   // 8
#define TNB  (ND/BN)     // 32

typedef __attribute__((ext_vector_type(8))) short          short8;
typedef __attribute__((ext_vector_type(8))) unsigned short us8;
typedef __attribute__((ext_vector_type(4))) float          f32x4;
typedef __attribute__((ext_vector_type(4))) unsigned short us4;

__device__ __forceinline__ unsigned short f2bf(float f) {
    union { float f; unsigned u; } v; v.f = f;
    unsigned u = v.u;
    return (unsigned short)((u + 0x7FFFu + ((u >> 16) & 1u)) >> 16);  // RNE
}

__device__ __forceinline__ void gload16(const void* g, void* l) {
    __builtin_amdgcn_global_load_lds(
        (const __attribute__((address_space(1))) void*)g,
        (__attribute__((address_space(3))) void*)l, 16, 0, 0);
}

// ---------------- Pass 1: fp32 -> bf16 conversion (memory-bound, ~5.6 TB/s) ---------
__global__ __launch_bounds__(256) void cvt_kernel(const float* __restrict__ src,
                                                  unsigned short* __restrict__ dst,
                                                  int n8) {
    int i = blockIdx.x * blockDim.x + threadIdx.x;
    int stride = gridDim.x * blockDim.x;
    for (; i < n8; i += stride) {
        const f32x4* s = (const f32x4*)(src + (size_t)i * 8);
        f32x4 a = s[0], b = s[1];
        us8 v = (us8){f2bf(a[0]), f2bf(a[1]), f2bf(a[2]), f2bf(a[3]),
                      f2bf(b[0]), f2bf(b[1]), f2bf(b[2]), f2bf(b[3])};
        *(us8*)(dst + (size_t)i * 8) = v;
    }
}

// ---------------- Pass 2: 8-phase 256x256 bf16 GEMM ----------------
// LDS regions: A[buf][khalf] 256x32 bf16 (16KB) x4 = 64KB; B same = 64KB. Total 128KB.
// Row stride 32 elems (64B). Swizzle: 16B-slot = kg ^ ((row>>1)&3) (read);
// write side achieved by pre-swizzled GLOBAL source on lane-linear gload_lds.
//
// Phase schedule per tile t (buf b = t&1), 4 phases:
//  p0: ldA(kh0) 8 + ldB(kh0,nh0) 2 | stageA(b^1, kh1, t+1) | BAR | MFMA mf0-7 x nf0-1 | BAR
//  p1: ldB(kh0,nh1) 2              | stageB(b^1, kh1, t+1) | BAR | MFMA nf2-3          | BAR
//  p2: ldA(kh1) 8 + ldB(kh1,nh0) 2 | stageA(b,   kh0, t+2) | BAR | MFMA nf0-1          | BAR
//  p3: ldB(kh1,nh1) 2              | stageB(b,   kh0, t+2) | BAR | MFMA nf2-3 |
//      vmcnt(4) [vmcnt(0) for last 2 tiles] | BAR
// Race ledger: each region's re-stage issue is >=2 barriers after its last read;
// vmcnt(4) at tile end forces the 8 oldest loads (tile t+1 data) landed, leaves
// the 4 newest (tile t+2 k0) in flight. Prologue: T0.k0, T0.k1, T1.k0 (12 loads),
// vmcnt(4) -> T0 landed, T1.k0 in flight. Steady thereafter.
__global__ __launch_bounds__(512, 2) void ggemm_8ph(
    const unsigned short* __restrict__ xb,  // [E][MAXM][KD] bf16
    const unsigned short* __restrict__ wb,  // [E][ND][KD]  bf16
    const int*   __restrict__ ms,
    float*       __restrict__ out)          // [E][MAXM][ND] fp32
{
    // XCD swizzle: 2048 blocks = 8 XCD x 256; each XCD gets one expert's 256 tiles.
    int orig = blockIdx.x;
    int cpx  = gridDim.x >> 3;
    int bid  = (orig & 7) * cpx + (orig >> 3);

    int e = bid >> 8;            // 256 tiles per expert
    int r = bid & 255;
    int g = r >> 5, u = r & 31;  // 32-resident supertile: 8 br x 4 bc
    int br = u >> 2;
    int bc = g * 4 + (u & 3);

    int m_size = ms[e];
    int row0 = br * BM, col0 = bc * BN;
    float* outE = out + (size_t)e * MAXM * ND;
    int tid = threadIdx.x;

    if (row0 >= m_size) {
        // fully-masked tile: zero-fill 256x256 fp32
        f32x4 z = (f32x4){0.f, 0.f, 0.f, 0.f};
        #pragma unroll
        for (int j = 0; j < 32; ++j) {
            int idx = tid + j * 512;           // f32x4 index, 64 per row
            int rr = idx >> 6, cc = (idx & 63) << 2;
            *(f32x4*)(outE + (size_t)(row0 + rr) * ND + col0 + cc) = z;
        }
        return;
    }

    const unsigned short* xE = xb + ((size_t)e * MAXM + row0) * KD;
    const unsigned short* wE = wb + ((size_t)e * ND   + col0) * KD;

    __shared__ unsigned short Ak[2][2][BM * 32];   // 64 KB
    __shared__ unsigned short Bk[2][2][BN * 32];   // 64 KB

    int wid = tid >> 6, lane = tid & 63;
    int wr = wid >> 2, wc = wid & 3;      // 2x4 wave grid; wave owns 128x64 of C
    int lr = lane & 15, kg = lane >> 4;
    int srow = lane >> 2;                 // staging: row within 16-row block
    int ss   = (lane & 3) ^ ((lane >> 3) & 3);  // pre-swizzled source slot (involution)

    // stage one K-half region (16KB) of A or B: 16 blocks of 1KB; wave wid does
    // blocks {2*wid, 2*wid+1}; LDS dest wave-uniform + lane*16 (lane-linear).
    auto stageA = [&](int b, int kh, int kt) {
        #pragma unroll
        for (int j = 0; j < 2; ++j) {
            int blk = wid * 2 + j;
            const unsigned short* src =
                xE + (size_t)(blk * 16 + srow) * KD + kt * BK + kh * 32 + ss * 8;
            gload16(src, (char*)&Ak[b][kh][0] + blk * 1024);
        }
    };
    auto stageB = [&](int b, int kh, int kt) {
        #pragma unroll
        for (int j = 0; j < 2; ++j) {
            int blk = wid * 2 + j;
            const unsigned short* src =
                wE + (size_t)(blk * 16 + srow) * KD + kt * BK + kh * 32 + ss * 8;
            gload16(src, (char*)&Bk[b][kh][0] + blk * 1024);
        }
    };

    auto ldA = [&](short8* a, int b, int kh) {
        #pragma unroll
        for (int mf = 0; mf < 8; ++mf) {
            int row  = wr * 128 + mf * 16 + lr;
            int slot = kg ^ ((row >> 1) & 3);
            a[mf] = *(const short8*)&Ak[b][kh][row * 32 + slot * 8];
        }
    };
    auto ldB = [&](short8* bf, int b, int kh, int nh) {
        #pragma unroll
        for (int i = 0; i < 2; ++i) {
            int row  = wc * 64 + (nh * 2 + i) * 16 + lr;
            int slot = kg ^ ((row >> 1) & 3);
            bf[i] = *(const short8*)&Bk[b][kh][row * 32 + slot * 8];
        }
    };

    f32x4 acc[8][4];
    #pragma unroll
    for (int mf = 0; mf < 8; ++mf)
        #pragma unroll
        for (int nf = 0; nf < 4; ++nf)
            acc[mf][nf] = (f32x4){0.f, 0.f, 0.f, 0.f};

    // prologue: T0 full + T1.k0 (12 loads/thread-pair pattern: 12 per thread? 12 issues total per thread = 6 calls x 2)
    stageA(0, 0, 0); stageB(0, 0, 0);
    stageA(0, 1, 0); stageB(0, 1, 0);
    stageA(1, 0, 1); stageB(1, 0, 1);
    asm volatile("s_waitcnt vmcnt(4)" ::: "memory");
    __builtin_amdgcn_s_barrier();

    auto tile = [&](int b, int t) {
        short8 a[8], bf[2];
        // ---- phase 0: kh0, nh0
        ldA(a, b, 0); ldB(bf, b, 0, 0);
        if (t + 1 < NT) stageA(b ^ 1, 1, t + 1);
        __builtin_amdgcn_s_barrier();
        __builtin_amdgcn_s_setprio(1);
        #pragma unroll
        for (int mf = 0; mf < 8; ++mf) {
            acc[mf][0] = __builtin_amdgcn_mfma_f32_16x16x32_bf16(a[mf], bf[0], acc[mf][0], 0, 0, 0);
            acc[mf][1] = __builtin_amdgcn_mfma_f32_16x16x32_bf16(a[mf], bf[1], acc[mf][1], 0, 0, 0);
        }
        __builtin_amdgcn_s_setprio(0);
        __builtin_amdgcn_s_barrier();
        // ---- phase 1: kh0, nh1
        ldB(bf, b, 0, 1);
        if (t + 1 < NT) stageB(b ^ 1, 1, t + 1);
        __builtin_amdgcn_s_barrier();
        __builtin_amdgcn_s_setprio(1);
        #pragma unroll
        for (int mf = 0; mf < 8; ++mf) {
            acc[mf][2] = __builtin_amdgcn_mfma_f32_16x16x32_bf16(a[mf], bf[0], acc[mf][2], 0, 0, 0);
            acc[mf][3] = __builtin_amdgcn_mfma_f32_16x16x32_bf16(a[mf], bf[1], acc[mf][3], 0, 0, 0);
        }
        __builtin_amdgcn_s_setprio(0);
        __builtin_amdgcn_s_barrier();
        // ---- phase 2: kh1, nh0
        ldA(a, b, 1); ldB(bf, b, 1, 0);
        if (t + 2 < NT) stageA(b, 0, t + 2);
        __builtin_amdgcn_s_barrier();
        __builtin_amdgcn_s_setprio(1);
        #pragma unroll
        for (int mf = 0; mf < 8; ++mf) {
            acc[mf][0] = __builtin_amdgcn_mfma_f32_16x16x32_bf16(a[mf], bf[0], acc[mf][0], 0, 0, 0);
            acc[mf][1] = __builtin_amdgcn_mfma_f32_16x16x32_bf16(a[mf], bf[1], acc[mf][1], 0, 0, 0);
        }
        __builtin_amdgcn_s_setprio(0);
        __builtin_amdgcn_s_barrier();
        // ---- phase 3: kh1, nh1
        ldB(bf, b, 1, 1);
        if (t + 2 < NT) stageB(b, 0, t + 2);
        __builtin_amdgcn_s_barrier();
        __builtin_amdgcn_s_setprio(1);
        #pragma unroll
        for (int mf = 0; mf < 8; ++mf) {
            acc[mf][2] = __builtin_amdgcn_mfma_f32_16x16x32_bf16(a[mf], bf[0], acc[mf][2], 0, 0, 0);
            acc[mf][3] = __builtin_amdgcn_mfma_f32_16x16x32_bf16(a[mf], bf[1], acc[mf][3], 0, 0, 0);
        }
        __builtin_amdgcn_s_setprio(0);
        if (t + 2 < NT) { asm volatile("s_waitcnt vmcnt(4)" ::: "memory"); }
        else            { asm volatile("s_waitcnt vmcnt(0)" ::: "memory"); }
        __builtin_amdgcn_s_barrier();
    };

    #pragma unroll 1
    for (int t = 0; t < NT; t += 2) {
        tile(0, t);
        tile(1, t + 1);
    }

    // epilogue: C/D 16x16x32 layout: col = lane&15, row = (lane>>4)*4 + j
    #pragma unroll
    for (int mf = 0; mf < 8; ++mf) {
        int rbase = row0 + wr * 128 + mf * 16 + kg * 4;
        #pragma unroll
        for (int nf = 0; nf < 4; ++nf) {
            int gc = col0 + wc * 64 + nf * 16 + lr;
            #pragma unroll
            for (int j = 0; j < 4; ++j) {
                int gr = rbase + j;
                float v = (gr < m_size) ? acc[mf][nf][j] : 0.f;
                outE[(size_t)gr * ND + gc] = v;
            }
        }
    }
}

// ---------------- Fallback: round-1 fused kernel (proven, used only if ws too small) --
#define FBM 128
#define FBK 32
#define FTM (MAXM/FBM)
#define FTN (ND/FBM)
#define FNT (KD/FBK)
#define LSTR 40
__global__ __launch_bounds__(256, 2) void ggemm_fused(
    const float* __restrict__ x, const float* __restrict__ w,
    const int* __restrict__ ms, float* __restrict__ out)
{
    int nwg  = gridDim.x;
    int orig = blockIdx.x;
    int cpx  = nwg >> 3;
    int bid  = (orig & 7) * cpx + (orig >> 3);
    int e   = bid / (FTM * FTN);
    int rem = bid % (FTM * FTN);
    int br  = rem % FTM;
    int bc  = rem / FTM;
    int m_size = ms[e];
    int row0 = br * FBM, col0 = bc * FBM;
    float* outE = out + (size_t)e * MAXM * ND;
    int tid = threadIdx.x;

    if (row0 >= m_size) {
        f32x4 z = (f32x4){0.f, 0.f, 0.f, 0.f};
        #pragma unroll
        for (int j = 0; j < 16; ++j) {
            int idx = tid + j * 256;
            int rr = idx >> 5, cc = (idx & 31) << 2;
            *(f32x4*)(outE + (size_t)(row0 + rr) * ND + col0 + cc) = z;
        }
        return;
    }

    const float* xE = x + ((size_t)e * MAXM + row0) * KD;
    const float* wE = w + ((size_t)e * ND   + col0) * KD;

    __shared__ unsigned short As[2][FBM][LSTR];
    __shared__ unsigned short Bs[2][FBM][LSTR];

    int sr  = tid >> 3;
    int sc4 = tid & 7;
    int wid = tid >> 6, lane = tid & 63;
    int wr = wid >> 1, wc = wid & 1;
    int lr = lane & 15, kg = lane >> 4;

    f32x4 acc[4][4];
    #pragma unroll
    for (int m = 0; m < 4; ++m)
        #pragma unroll
        for (int n = 0; n < 4; ++n)
            acc[m][n] = (f32x4){0.f, 0.f, 0.f, 0.f};

    {
        #pragma unroll
        for (int j = 0; j < 4; ++j) {
            int r0 = sr + j * 32;
            f32x4 av = *(const f32x4*)(xE + (size_t)r0 * KD + sc4 * 4);
            f32x4 bv = *(const f32x4*)(wE + (size_t)r0 * KD + sc4 * 4);
            us4 ah = (us4){f2bf(av[0]), f2bf(av[1]), f2bf(av[2]), f2bf(av[3])};
            us4 bh = (us4){f2bf(bv[0]), f2bf(bv[1]), f2bf(bv[2]), f2bf(bv[3])};
            *(us4*)&As[0][r0][sc4 * 4] = ah;
            *(us4*)&Bs[0][r0][sc4 * 4] = bh;
        }
    }
    __syncthreads();

    for (int t = 0; t < FNT; ++t) {
        int cur = t & 1;
        f32x4 av[4], bv[4];
        bool pre = (t + 1 < FNT);
        if (pre) {
            const float* xk = xE + (size_t)(t + 1) * FBK;
            const float* wk = wE + (size_t)(t + 1) * FBK;
            #pragma unroll
            for (int j = 0; j < 4; ++j) {
                int r0 = sr + j * 32;
                av[j] = *(const f32x4*)(xk + (size_t)r0 * KD + sc4 * 4);
                bv[j] = *(const f32x4*)(wk + (size_t)r0 * KD + sc4 * 4);
            }
        }
        short8 a[4], b[4];
        #pragma unroll
        for (int m = 0; m < 4; ++m)
            a[m] = *(const short8*)&As[cur][wr * 64 + m * 16 + lr][kg * 8];
        #pragma unroll
        for (int n = 0; n < 4; ++n)
            b[n] = *(const short8*)&Bs[cur][wc * 64 + n * 16 + lr][kg * 8];
        #pragma unroll
        for (int m = 0; m < 4; ++m)
            #pragma unroll
            for (int n = 0; n < 4; ++n)
                acc[m][n] = __builtin_amdgcn_mfma_f32_16x16x32_bf16(a[m], b[n], acc[m][n], 0, 0, 0);

        if (pre) {
            int nb = cur ^ 1;
            #pragma unroll
            for (int j = 0; j < 4; ++j) {
                int r0 = sr + j * 32;
                us4 ah = (us4){f2bf(av[j][0]), f2bf(av[j][1]), f2bf(av[j][2]), f2bf(av[j][3])};
                us4 bh = (us4){f2bf(bv[j][0]), f2bf(bv[j][1]), f2bf(bv[j][2]), f2bf(bv[j][3])};
                *(us4*)&As[nb][r0][sc4 * 4] = ah;
                *(us4*)&Bs[nb][r0][sc4 * 4] = bh;
            }
        }
        __syncthreads();
    }

    #pragma unroll
    for (int m = 0; m < 4; ++m) {
        int rbase = row0 + wr * 64 + m * 16 + kg * 4;
        #pragma unroll
        for (int n = 0; n < 4; ++n) {
            int gc = col0 + wc * 64 + n * 16 + lr;
            #pragma unroll
            for (int j = 0; j < 4; ++j) {
                int gr = rbase + j;
                float v = (gr < m_size) ? acc[m][n][j] : 0.f;
                outE[(size_t)gr * ND + gc] = v;
            }
        }
    }
}

extern "C" void kernel_launch(void* const* d_in, const int* in_sizes, int n_in,
                              void* d_out, int out_size, void* d_ws, size_t ws_size,
                              hipStream_t stream) {
    const float* x  = (const float*)d_in[0];
    const float* w  = (const float*)d_in[1];
    const int*   ms = (const int*)d_in[2];
    float* out = (float*)d_out;

    const size_t xElems = (size_t)NE * MAXM * KD;   // 33,554,432
    const size_t wElems = (size_t)NE * ND   * KD;   // 134,217,728
    const size_t need   = (xElems + wElems) * 2;    // 335,544,320 B

    if (ws_size >= need) {
        unsigned short* xb = (unsigned short*)d_ws;
        unsigned short* wb = xb + xElems;
        cvt_kernel<<<2048, 256, 0, stream>>>(x, xb, (int)(xElems / 8));
        cvt_kernel<<<2048, 256, 0, stream>>>(w, wb, (int)(wElems / 8));
        ggemm_8ph<<<dim3(NE * TMB * TNB), dim3(512), 0, stream>>>(xb, wb, ms, out);
    } else {
        ggemm_fused<<<dim3(NE * (MAXM/FBM) * (ND/FBM)), dim3(256), 0, stream>>>(x, w, ms, out);
    }
}

// Round 4
// 600.296 us; speedup vs baseline: 1.4762x; 1.1562x over previous
//
#include <hip/hip_runtime.h>
#include <hip/hip_bf16.h>

// BMMGroupedGEMM: out[e,m,n] = sum_k x[e,m,k] * w[e,n,k], rows m >= m_sizes[e] zeroed.
// E=8, MAX_M=2048, K=2048, N=8192. fp32 in/out.
// Round 4: (a) XCD-balanced block mapping -- each XCD owns bc-group==xcd of EVERY
// expert, so per-XCD work is identical regardless of m_sizes skew (round-3 pinned
// one expert per XCD -> makespan = heaviest expert). (b) deeper counted vmcnt:
// vmcnt(8) at p1-end AND p3-end (ledger below) so every staged load gets ~4-5
// phases of flight (~>=800 cy) instead of 3.

#define NE   8
#define MAXM 2048
#define KD   2048
#define ND   8192

// 8-phase GEMM geometry
#define BM   256
#define BN   256
#define BK   64
#define NT   (KD/BK)     // 32
#define TMB  (MAXM/BM)   // 8
#define TNB  (ND/BN)     // 32

typedef __attribute__((ext_vector_type(8))) short          short8;
typedef __attribute__((ext_vector_type(8))) unsigned short us8;
typedef __attribute__((ext_vector_type(4))) float          f32x4;
typedef __attribute__((ext_vector_type(4))) unsigned short us4;

__device__ __forceinline__ unsigned short f2bf(float f) {
    union { float f; unsigned u; } v; v.f = f;
    unsigned u = v.u;
    return (unsigned short)((u + 0x7FFFu + ((u >> 16) & 1u)) >> 16);  // RNE
}

__device__ __forceinline__ void gload16(const void* g, void* l) {
    __builtin_amdgcn_global_load_lds(
        (const __attribute__((address_space(1))) void*)g,
        (__attribute__((address_space(3))) void*)l, 16, 0, 0);
}

// ---------------- Pass 1: fp32 -> bf16 conversion (memory-bound) ----------------
__global__ __launch_bounds__(256) void cvt_kernel(const float* __restrict__ src,
                                                  unsigned short* __restrict__ dst,
                                                  int n8) {
    int i = blockIdx.x * blockDim.x + threadIdx.x;
    int stride = gridDim.x * blockDim.x;
    for (; i < n8; i += stride) {
        const f32x4* s = (const f32x4*)(src + (size_t)i * 8);
        f32x4 a = s[0], b = s[1];
        us8 v = (us8){f2bf(a[0]), f2bf(a[1]), f2bf(a[2]), f2bf(a[3]),
                      f2bf(b[0]), f2bf(b[1]), f2bf(b[2]), f2bf(b[3])};
        *(us8*)(dst + (size_t)i * 8) = v;
    }
}

// ---------------- Pass 2: 8-phase 256x256 bf16 GEMM ----------------
// LDS: A[buf][khalf] 256x32 bf16 (16KB) x4 = 64KB; B same = 64KB. Total 128KB.
// Read swizzle slot = kg ^ ((row>>1)&3); write side via pre-swizzled GLOBAL source
// (same involution) on the lane-linear global_load_lds dest (rule: both sides).
//
// Phase schedule per tile t (buf b = t&1), 4 phases x {ds_read | stage | BAR |
// setprio(1) 16 MFMA setprio(0) | [vmcnt] BAR}:
//  p0: ldA(kh0)+ldB(kh0,nh0) | stageA(b^1,kh1,t+1)
//  p1: ldB(kh0,nh1)          | stageB(b^1,kh1,t+1) | vmcnt(8) at end
//  p2: ldA(kh1)+ldB(kh1,nh0) | stageA(b,  kh0,t+2)
//  p3: ldB(kh1,nh1)          | stageB(b,  kh0,t+2) | vmcnt(8) at end
// Ledger (steady, 2 loads/wave per stage): entering t outstanding = 8
// {kh1(t) 4, kh0(t+1) 4}; p0/p1 issue 4 -> 12; p1-end vmcnt(8) drains kh1(t)
// (needed at p2 read) -> {kh0(t+1), kh1(t+1)}; p2/p3 issue 4 -> 12; p3-end
// vmcnt(8) drains kh0(t+1) (needed at t+1 p0 read). Tail: p1-end 8 if t+1<NT
// else 0; p3-end 8/4/0 per guards. Every load gets >=4 phases of flight.
__global__ __launch_bounds__(512, 2) void ggemm_8ph(
    const unsigned short* __restrict__ xb,  // [E][MAXM][KD] bf16
    const unsigned short* __restrict__ wb,  // [E][ND][KD]  bf16
    const int*   __restrict__ ms,
    float*       __restrict__ out)          // [E][MAXM][ND] fp32
{
    // XCD-balanced mapping: xcd = orig&7 (HW round-robin). XCD k owns bc-group k
    // of EVERY expert: idx = orig>>3 in [0,256): e = idx>>5, u = idx&31,
    // br = u>>2 (8), bc = xcd*4 + (u&3). Every XCD queue has the identical
    // expert mix -> balanced regardless of m_sizes. B panels XCD-exclusive;
    // A panels (small) re-fetched per XCD.
    int orig = blockIdx.x;
    int xcd  = orig & 7;
    int idx  = orig >> 3;
    int e    = idx >> 5;
    int u    = idx & 31;
    int br   = u >> 2;
    int bc   = xcd * 4 + (u & 3);

    int m_size = ms[e];
    int row0 = br * BM, col0 = bc * BN;
    float* outE = out + (size_t)e * MAXM * ND;
    int tid = threadIdx.x;

    if (row0 >= m_size) {
        // fully-masked tile: zero-fill 256x256 fp32
        f32x4 z = (f32x4){0.f, 0.f, 0.f, 0.f};
        #pragma unroll
        for (int j = 0; j < 32; ++j) {
            int i2 = tid + j * 512;            // f32x4 index, 64 per row
            int rr = i2 >> 6, cc = (i2 & 63) << 2;
            *(f32x4*)(outE + (size_t)(row0 + rr) * ND + col0 + cc) = z;
        }
        return;
    }

    const unsigned short* xE = xb + ((size_t)e * MAXM + row0) * KD;
    const unsigned short* wE = wb + ((size_t)e * ND   + col0) * KD;

    __shared__ unsigned short Ak[2][2][BM * 32];   // 64 KB
    __shared__ unsigned short Bk[2][2][BN * 32];   // 64 KB

    int wid = tid >> 6, lane = tid & 63;
    int wr = wid >> 2, wc = wid & 3;      // 2x4 wave grid; wave owns 128x64 of C
    int lr = lane & 15, kg = lane >> 4;
    int srow = lane >> 2;                 // staging: row within 16-row block
    int ss   = (lane & 3) ^ ((lane >> 3) & 3);  // pre-swizzled source slot (involution)

    auto stageA = [&](int b, int kh, int kt) {
        #pragma unroll
        for (int j = 0; j < 2; ++j) {
            int blk = wid * 2 + j;
            const unsigned short* src =
                xE + (size_t)(blk * 16 + srow) * KD + kt * BK + kh * 32 + ss * 8;
            gload16(src, (char*)&Ak[b][kh][0] + blk * 1024);
        }
    };
    auto stageB = [&](int b, int kh, int kt) {
        #pragma unroll
        for (int j = 0; j < 2; ++j) {
            int blk = wid * 2 + j;
            const unsigned short* src =
                wE + (size_t)(blk * 16 + srow) * KD + kt * BK + kh * 32 + ss * 8;
            gload16(src, (char*)&Bk[b][kh][0] + blk * 1024);
        }
    };

    auto ldA = [&](short8* a, int b, int kh) {
        #pragma unroll
        for (int mf = 0; mf < 8; ++mf) {
            int row  = wr * 128 + mf * 16 + lr;
            int slot = kg ^ ((row >> 1) & 3);
            a[mf] = *(const short8*)&Ak[b][kh][row * 32 + slot * 8];
        }
    };
    auto ldB = [&](short8* bf, int b, int kh, int nh) {
        #pragma unroll
        for (int i = 0; i < 2; ++i) {
            int row  = wc * 64 + (nh * 2 + i) * 16 + lr;
            int slot = kg ^ ((row >> 1) & 3);
            bf[i] = *(const short8*)&Bk[b][kh][row * 32 + slot * 8];
        }
    };

    f32x4 acc[8][4];
    #pragma unroll
    for (int mf = 0; mf < 8; ++mf)
        #pragma unroll
        for (int nf = 0; nf < 4; ++nf)
            acc[mf][nf] = (f32x4){0.f, 0.f, 0.f, 0.f};

    // prologue: T0.k0, T0.k1, T1.k0 (12 loads/wave); drain T0.k0 only.
    stageA(0, 0, 0); stageB(0, 0, 0);
    stageA(0, 1, 0); stageB(0, 1, 0);
    stageA(1, 0, 1); stageB(1, 0, 1);
    asm volatile("s_waitcnt vmcnt(8)" ::: "memory");
    __builtin_amdgcn_s_barrier();

    auto tile = [&](int b, int t) {
        short8 a[8], bf[2];
        // ---- phase 0: kh0, nh0
        ldA(a, b, 0); ldB(bf, b, 0, 0);
        if (t + 1 < NT) stageA(b ^ 1, 1, t + 1);
        __builtin_amdgcn_s_barrier();
        __builtin_amdgcn_s_setprio(1);
        #pragma unroll
        for (int mf = 0; mf < 8; ++mf) {
            acc[mf][0] = __builtin_amdgcn_mfma_f32_16x16x32_bf16(a[mf], bf[0], acc[mf][0], 0, 0, 0);
            acc[mf][1] = __builtin_amdgcn_mfma_f32_16x16x32_bf16(a[mf], bf[1], acc[mf][1], 0, 0, 0);
        }
        __builtin_amdgcn_s_setprio(0);
        __builtin_amdgcn_s_barrier();
        // ---- phase 1: kh0, nh1
        ldB(bf, b, 0, 1);
        if (t + 1 < NT) stageB(b ^ 1, 1, t + 1);
        __builtin_amdgcn_s_barrier();
        __builtin_amdgcn_s_setprio(1);
        #pragma unroll
        for (int mf = 0; mf < 8; ++mf) {
            acc[mf][2] = __builtin_amdgcn_mfma_f32_16x16x32_bf16(a[mf], bf[0], acc[mf][2], 0, 0, 0);
            acc[mf][3] = __builtin_amdgcn_mfma_f32_16x16x32_bf16(a[mf], bf[1], acc[mf][3], 0, 0, 0);
        }
        __builtin_amdgcn_s_setprio(0);
        if (t + 1 < NT) { asm volatile("s_waitcnt vmcnt(8)" ::: "memory"); }
        else            { asm volatile("s_waitcnt vmcnt(0)" ::: "memory"); }
        __builtin_amdgcn_s_barrier();
        // ---- phase 2: kh1, nh0
        ldA(a, b, 1); ldB(bf, b, 1, 0);
        if (t + 2 < NT) stageA(b, 0, t + 2);
        __builtin_amdgcn_s_barrier();
        __builtin_amdgcn_s_setprio(1);
        #pragma unroll
        for (int mf = 0; mf < 8; ++mf) {
            acc[mf][0] = __builtin_amdgcn_mfma_f32_16x16x32_bf16(a[mf], bf[0], acc[mf][0], 0, 0, 0);
            acc[mf][1] = __builtin_amdgcn_mfma_f32_16x16x32_bf16(a[mf], bf[1], acc[mf][1], 0, 0, 0);
        }
        __builtin_amdgcn_s_setprio(0);
        __builtin_amdgcn_s_barrier();
        // ---- phase 3: kh1, nh1
        ldB(bf, b, 1, 1);
        if (t + 2 < NT) stageB(b, 0, t + 2);
        __builtin_amdgcn_s_barrier();
        __builtin_amdgcn_s_setprio(1);
        #pragma unroll
        for (int mf = 0; mf < 8; ++mf) {
            acc[mf][2] = __builtin_amdgcn_mfma_f32_16x16x32_bf16(a[mf], bf[0], acc[mf][2], 0, 0, 0);
            acc[mf][3] = __builtin_amdgcn_mfma_f32_16x16x32_bf16(a[mf], bf[1], acc[mf][3], 0, 0, 0);
        }
        __builtin_amdgcn_s_setprio(0);
        if (t + 2 < NT)      { asm volatile("s_waitcnt vmcnt(8)" ::: "memory"); }
        else if (t + 1 < NT) { asm volatile("s_waitcnt vmcnt(4)" ::: "memory"); }
        else                 { asm volatile("s_waitcnt vmcnt(0)" ::: "memory"); }
        __builtin_amdgcn_s_barrier();
    };

    #pragma unroll 1
    for (int t = 0; t < NT; t += 2) {
        tile(0, t);
        tile(1, t + 1);
    }

    // epilogue: C/D 16x16x32 layout: col = lane&15, row = (lane>>4)*4 + j
    #pragma unroll
    for (int mf = 0; mf < 8; ++mf) {
        int rbase = row0 + wr * 128 + mf * 16 + kg * 4;
        #pragma unroll
        for (int nf = 0; nf < 4; ++nf) {
            int gc = col0 + wc * 64 + nf * 16 + lr;
            #pragma unroll
            for (int j = 0; j < 4; ++j) {
                int gr = rbase + j;
                float v = (gr < m_size) ? acc[mf][nf][j] : 0.f;
                outE[(size_t)gr * ND + gc] = v;
            }
        }
    }
}

// ---------------- Fallback: round-1 fused kernel (used only if ws too small) --------
#define FBM 128
#define FBK 32
#define FTM (MAXM/FBM)
#define FTN (ND/FBM)
#define FNT (KD/FBK)
#define LSTR 40
__global__ __launch_bounds__(256, 2) void ggemm_fused(
    const float* __restrict__ x, const float* __restrict__ w,
    const int* __restrict__ ms, float* __restrict__ out)
{
    int nwg  = gridDim.x;
    int orig = blockIdx.x;
    int cpx  = nwg >> 3;
    int bid  = (orig & 7) * cpx + (orig >> 3);
    int e   = bid / (FTM * FTN);
    int rem = bid % (FTM * FTN);
    int br  = rem % FTM;
    int bc  = rem / FTM;
    int m_size = ms[e];
    int row0 = br * FBM, col0 = bc * FBM;
    float* outE = out + (size_t)e * MAXM * ND;
    int tid = threadIdx.x;

    if (row0 >= m_size) {
        f32x4 z = (f32x4){0.f, 0.f, 0.f, 0.f};
        #pragma unroll
        for (int j = 0; j < 16; ++j) {
            int i2 = tid + j * 256;
            int rr = i2 >> 5, cc = (i2 & 31) << 2;
            *(f32x4*)(outE + (size_t)(row0 + rr) * ND + col0 + cc) = z;
        }
        return;
    }

    const float* xE = x + ((size_t)e * MAXM + row0) * KD;
    const float* wE = w + ((size_t)e * ND   + col0) * KD;

    __shared__ unsigned short As[2][FBM][LSTR];
    __shared__ unsigned short Bs[2][FBM][LSTR];

    int sr  = tid >> 3;
    int sc4 = tid & 7;
    int wid = tid >> 6, lane = tid & 63;
    int wr = wid >> 1, wc = wid & 1;
    int lr = lane & 15, kg = lane >> 4;

    f32x4 acc[4][4];
    #pragma unroll
    for (int m = 0; m < 4; ++m)
        #pragma unroll
        for (int n = 0; n < 4; ++n)
            acc[m][n] = (f32x4){0.f, 0.f, 0.f, 0.f};

    {
        #pragma unroll
        for (int j = 0; j < 4; ++j) {
            int r0 = sr + j * 32;
            f32x4 av = *(const f32x4*)(xE + (size_t)r0 * KD + sc4 * 4);
            f32x4 bv = *(const f32x4*)(wE + (size_t)r0 * KD + sc4 * 4);
            us4 ah = (us4){f2bf(av[0]), f2bf(av[1]), f2bf(av[2]), f2bf(av[3])};
            us4 bh = (us4){f2bf(bv[0]), f2bf(bv[1]), f2bf(bv[2]), f2bf(bv[3])};
            *(us4*)&As[0][r0][sc4 * 4] = ah;
            *(us4*)&Bs[0][r0][sc4 * 4] = bh;
        }
    }
    __syncthreads();

    for (int t = 0; t < FNT; ++t) {
        int cur = t & 1;
        f32x4 av[4], bv[4];
        bool pre = (t + 1 < FNT);
        if (pre) {
            const float* xk = xE + (size_t)(t + 1) * FBK;
            const float* wk = wE + (size_t)(t + 1) * FBK;
            #pragma unroll
            for (int j = 0; j < 4; ++j) {
                int r0 = sr + j * 32;
                av[j] = *(const f32x4*)(xk + (size_t)r0 * KD + sc4 * 4);
                bv[j] = *(const f32x4*)(wk + (size_t)r0 * KD + sc4 * 4);
            }
        }
        short8 a[4], b[4];
        #pragma unroll
        for (int m = 0; m < 4; ++m)
            a[m] = *(const short8*)&As[cur][wr * 64 + m * 16 + lr][kg * 8];
        #pragma unroll
        for (int n = 0; n < 4; ++n)
            b[n] = *(const short8*)&Bs[cur][wc * 64 + n * 16 + lr][kg * 8];
        #pragma unroll
        for (int m = 0; m < 4; ++m)
            #pragma unroll
            for (int n = 0; n < 4; ++n)
                acc[m][n] = __builtin_amdgcn_mfma_f32_16x16x32_bf16(a[m], b[n], acc[m][n], 0, 0, 0);

        if (pre) {
            int nb = cur ^ 1;
            #pragma unroll
            for (int j = 0; j < 4; ++j) {
                int r0 = sr + j * 32;
                us4 ah = (us4){f2bf(av[j][0]), f2bf(av[j][1]), f2bf(av[j][2]), f2bf(av[j][3])};
                us4 bh = (us4){f2bf(bv[j][0]), f2bf(bv[j][1]), f2bf(bv[j][2]), f2bf(bv[j][3])};
                *(us4*)&As[nb][r0][sc4 * 4] = ah;
                *(us4*)&Bs[nb][r0][sc4 * 4] = bh;
            }
        }
        __syncthreads();
    }

    #pragma unroll
    for (int m = 0; m < 4; ++m) {
        int rbase = row0 + wr * 64 + m * 16 + kg * 4;
        #pragma unroll
        for (int n = 0; n < 4; ++n) {
            int gc = col0 + wc * 64 + n * 16 + lr;
            #pragma unroll
            for (int j = 0; j < 4; ++j) {
                int gr = rbase + j;
                float v = (gr < m_size) ? acc[m][n][j] : 0.f;
                outE[(size_t)gr * ND + gc] = v;
            }
        }
    }
}

extern "C" void kernel_launch(void* const* d_in, const int* in_sizes, int n_in,
                              void* d_out, int out_size, void* d_ws, size_t ws_size,
                              hipStream_t stream) {
    const float* x  = (const float*)d_in[0];
    const float* w  = (const float*)d_in[1];
    const int*   ms = (const int*)d_in[2];
    float* out = (float*)d_out;

    const size_t xElems = (size_t)NE * MAXM * KD;   // 33,554,432
    const size_t wElems = (size_t)NE * ND   * KD;   // 134,217,728
    const size_t need   = (xElems + wElems) * 2;    // 335,544,320 B

    if (ws_size >= need) {
        unsigned short* xb = (unsigned short*)d_ws;
        unsigned short* wb = xb + xElems;
        cvt_kernel<<<2048, 256, 0, stream>>>(x, xb, (int)(xElems / 8));
        cvt_kernel<<<2048, 256, 0, stream>>>(w, wb, (int)(wElems / 8));
        ggemm_8ph<<<dim3(NE * TMB * TNB), dim3(512), 0, stream>>>(xb, wb, ms, out);
    } else {
        ggemm_fused<<<dim3(NE * (MAXM/FBM) * (ND/FBM)), dim3(256), 0, stream>>>(x, w, ms, out);
    }
}

// Round 5
// 583.855 us; speedup vs baseline: 1.5178x; 1.0282x over previous
//
#include <hip/hip_runtime.h>
#include <hip/hip_bf16.h>

// BMMGroupedGEMM: out[e,m,n] = sum_k x[e,m,k] * w[e,n,k], rows m >= m_sizes[e] zeroed.
// E=8, MAX_M=2048, K=2048, N=8192. fp32 in/out.
// Round 5: persistent-block GEMM. Grid=256 (1 block/CU). Block owns one (br,bc)
// tile of EVERY expert (br=(rrot+e)&7 rotation -> balanced). Dead tiles zero-filled
// up-front; live tiles run as ONE continuous virtual-K pipeline (stage ring and
// counted-vmcnt ledger continue across tile boundaries; epilogue stores overlap
// next tile's prefetch). Wave-level MFMA skip for fully-masked 128-row halves.
// cvt-x skips masked rows (garbage feeds only masked, row-local outputs).

#define NE   8
#define MAXM 2048
#define KD   2048
#define ND   8192

#define BM   256
#define BN   256
#define BK   64
#define NTS  (KD/BK)     // 32 K-tiles per output tile

typedef __attribute__((ext_vector_type(8))) short          short8;
typedef __attribute__((ext_vector_type(8))) unsigned short us8;
typedef __attribute__((ext_vector_type(4))) float          f32x4;
typedef __attribute__((ext_vector_type(4))) unsigned short us4;

__device__ __forceinline__ unsigned short f2bf(float f) {
    union { float f; unsigned u; } v; v.f = f;
    unsigned u = v.u;
    return (unsigned short)((u + 0x7FFFu + ((u >> 16) & 1u)) >> 16);  // RNE
}

__device__ __forceinline__ void gload16(const void* g, void* l) {
    __builtin_amdgcn_global_load_lds(
        (const __attribute__((address_space(1))) void*)g,
        (__attribute__((address_space(3))) void*)l, 16, 0, 0);
}

// ---------------- Pass 1a: fp32 -> bf16 for W (full) ----------------
__global__ __launch_bounds__(256) void cvt_kernel(const float* __restrict__ src,
                                                  unsigned short* __restrict__ dst,
                                                  int n8) {
    int i = blockIdx.x * blockDim.x + threadIdx.x;
    int stride = gridDim.x * blockDim.x;
    for (; i < n8; i += stride) {
        const f32x4* s = (const f32x4*)(src + (size_t)i * 8);
        f32x4 a = s[0], b = s[1];
        us8 v = (us8){f2bf(a[0]), f2bf(a[1]), f2bf(a[2]), f2bf(a[3]),
                      f2bf(b[0]), f2bf(b[1]), f2bf(b[2]), f2bf(b[3])};
        *(us8*)(dst + (size_t)i * 8) = v;
    }
}

// ---------------- Pass 1b: fp32 -> bf16 for X, masked rows skipped ----------------
// Skipped rows leave d_ws garbage (0xAA poison = tiny bf16 denormal, or stale):
// staged into partial tiles but products land only in masked, row-local outputs,
// which the epilogue overwrites with literal 0. Deterministic: we never write them.
__global__ __launch_bounds__(256) void cvt_x_kernel(const float* __restrict__ src,
                                                    unsigned short* __restrict__ dst,
                                                    const int* __restrict__ ms) {
    int bid = blockIdx.x;            // E*MAXM = 16384 rows
    int e = bid >> 11, m = bid & 2047;
    if (m >= ms[e]) return;
    const float* s = src + ((size_t)e * MAXM + m) * KD;
    unsigned short* d = dst + ((size_t)e * MAXM + m) * KD;
    int t = threadIdx.x;             // 256 threads x 8 elems = 2048
    const f32x4* s4 = (const f32x4*)(s + t * 8);
    f32x4 a = s4[0], b = s4[1];
    us8 v = (us8){f2bf(a[0]), f2bf(a[1]), f2bf(a[2]), f2bf(a[3]),
                  f2bf(b[0]), f2bf(b[1]), f2bf(b[2]), f2bf(b[3])};
    *(us8*)(d + t * 8) = v;
}

// ---------------- Pass 2: persistent 8-phase 256x256 bf16 GEMM ----------------
// LDS: A[buf][kh] 256x32 bf16 (16KB) x4 = 64KB; B same = 64KB. Total 128KB.
// Read swizzle slot = kg ^ ((row>>1)&3); write side via pre-swizzled GLOBAL source.
// Virtual-K ledger (identical to round 4, pointers switch at tile boundaries):
//  p0: ldA(kh0)+ldB(kh0,nh0) | stageA(b^1,kh1,vk+1)
//  p1: ldB(kh0,nh1)          | stageB(b^1,kh1,vk+1) | vmcnt(8) at end
//  p2: ldA(kh1)+ldB(kh1,nh0) | stageA(b,  kh0,vk+2)
//  p3: ldB(kh1,nh1)          | stageB(b,  kh0,vk+2) | vmcnt(8) at end
// Entering vk: outstanding 8 = {kh1(vk):4, kh0(vk+1):4}; p1-end vmcnt(8) drains
// kh1(vk) (read p2), p3-end vmcnt(8) drains kh0(vk+1) (read vk+1 p0); every load
// gets 5-6 phases of flight. Tail (end of last live tile): p1-end 8/0; p3-end 8/4/0.
__global__ __launch_bounds__(512, 2) void ggemm_pers(
    const unsigned short* __restrict__ xb,  // [E][MAXM][KD] bf16
    const unsigned short* __restrict__ wb,  // [E][ND][KD]  bf16
    const int*   __restrict__ ms,
    float*       __restrict__ out)          // [E][MAXM][ND] fp32
{
    int p    = blockIdx.x;         // 256 blocks, 1 per CU
    int xcd  = p & 7;              // HW round-robins consecutive blockIdx over XCDs
    int q    = p >> 3;             // 0..31 within XCD
    int rrot = q >> 2;             // 0..7 expert->br rotation
    int bc   = xcd * 4 + (q & 3);
    int col0 = bc * BN;
    int tid  = threadIdx.x;

    __shared__ int s_live[8];
    __shared__ int s_nlive;
    __shared__ unsigned short Ak[2][2][BM * 32];   // 64 KB
    __shared__ unsigned short Bk[2][2][BN * 32];   // 64 KB

    if (tid == 0) {
        int n = 0;
        #pragma unroll
        for (int e = 0; e < NE; ++e) {
            int br = (rrot + e) & 7;
            if (br * BM < ms[e]) { s_live[n] = (e << 3) | br; ++n; }
        }
        s_nlive = n;
    }

    // zero-fill dead tiles up-front (overlaps other blocks' compute)
    #pragma unroll 1
    for (int e = 0; e < NE; ++e) {
        int br   = (rrot + e) & 7;
        int row0 = br * BM;
        if (row0 >= ms[e]) {
            float* outE = out + (size_t)e * MAXM * ND;
            f32x4 z = (f32x4){0.f, 0.f, 0.f, 0.f};
            #pragma unroll
            for (int j = 0; j < 32; ++j) {
                int i2 = tid + j * 512;
                int rr = i2 >> 6, cc = (i2 & 63) << 2;
                *(f32x4*)(outE + (size_t)(row0 + rr) * ND + col0 + cc) = z;
            }
        }
    }
    __syncthreads();
    int nlive = s_nlive;
    if (nlive == 0) return;

    int wid = tid >> 6, lane = tid & 63;
    int wr = wid >> 2, wc = wid & 3;            // 2x4 wave grid; wave owns 128x64
    int lr = lane & 15, kg = lane >> 4;
    int srow = lane >> 2;
    int ss   = (lane & 3) ^ ((lane >> 3) & 3);  // pre-swizzled source slot

    auto stageA = [&](int b, int kh, const unsigned short* xP, int kt) {
        #pragma unroll
        for (int j = 0; j < 2; ++j) {
            int blk = wid * 2 + j;
            const unsigned short* src =
                xP + (size_t)(blk * 16 + srow) * KD + kt * BK + kh * 32 + ss * 8;
            gload16(src, (char*)&Ak[b][kh][0] + blk * 1024);
        }
    };
    auto stageB = [&](int b, int kh, const unsigned short* wP, int kt) {
        #pragma unroll
        for (int j = 0; j < 2; ++j) {
            int blk = wid * 2 + j;
            const unsigned short* src =
                wP + (size_t)(blk * 16 + srow) * KD + kt * BK + kh * 32 + ss * 8;
            gload16(src, (char*)&Bk[b][kh][0] + blk * 1024);
        }
    };
    auto ldA = [&](short8* a, int b, int kh) {
        #pragma unroll
        for (int mf = 0; mf < 8; ++mf) {
            int row  = wr * 128 + mf * 16 + lr;
            int slot = kg ^ ((row >> 1) & 3);
            a[mf] = *(const short8*)&Ak[b][kh][row * 32 + slot * 8];
        }
    };
    auto ldB = [&](short8* bf, int b, int kh, int nh) {
        #pragma unroll
        for (int i = 0; i < 2; ++i) {
            int row  = wc * 64 + (nh * 2 + i) * 16 + lr;
            int slot = kg ^ ((row >> 1) & 3);
            bf[i] = *(const short8*)&Bk[b][kh][row * 32 + slot * 8];
        }
    };

    f32x4 acc[8][4];
    #pragma unroll
    for (int mf = 0; mf < 8; ++mf)
        #pragma unroll
        for (int nf = 0; nf < 4; ++nf)
            acc[mf][nf] = (f32x4){0.f, 0.f, 0.f, 0.f};

    // slot metadata (cur / next), shifted at each tile boundary
    const unsigned short *xC, *wC, *xN, *wN;
    float *oC, *oN;
    int msC, r0C, msN, r0N;
    {
        int v = s_live[0]; int e = v >> 3, br = v & 7;
        r0C = br * BM; msC = ms[e];
        xC = xb + ((size_t)e * MAXM + r0C) * KD;
        wC = wb + ((size_t)e * ND + col0) * KD;
        oC = out + (size_t)e * MAXM * ND;
    }
    if (nlive > 1) {
        int v = s_live[1]; int e = v >> 3, br = v & 7;
        r0N = br * BM; msN = ms[e];
        xN = xb + ((size_t)e * MAXM + r0N) * KD;
        wN = wb + ((size_t)e * ND + col0) * KD;
        oN = out + (size_t)e * MAXM * ND;
    } else { xN = xC; wN = wC; oN = oC; msN = msC; r0N = r0C; }

    // prologue: vk0.{kh0,kh1} + vk1.kh0 (slot 0 always has kt 0 and 1)
    stageA(0, 0, xC, 0); stageB(0, 0, wC, 0);
    stageA(0, 1, xC, 0); stageB(0, 1, wC, 0);
    stageA(1, 0, xC, 1); stageB(1, 0, wC, 1);
    asm volatile("s_waitcnt vmcnt(8)" ::: "memory");
    __builtin_amdgcn_s_barrier();

    #pragma unroll 1
    for (int s = 0; s < nlive; ++s) {
        bool last  = (s + 1 >= nlive);
        bool alive = (r0C + wr * 128) < msC;   // wave-uniform: MFMA/ldX skip for dead half

        auto tile = [&](int b, int kt) {
            bool g1 = (kt + 1 < NTS) || (!last);
            bool g2 = (kt + 2 < NTS) || (!last);
            const unsigned short* xS1 = (kt + 1 < NTS) ? xC : xN;
            const unsigned short* wS1 = (kt + 1 < NTS) ? wC : wN;
            int k1 = (kt + 1 < NTS) ? kt + 1 : 0;
            const unsigned short* xS2 = (kt + 2 < NTS) ? xC : xN;
            const unsigned short* wS2 = (kt + 2 < NTS) ? wC : wN;
            int k2 = (kt + 2 < NTS) ? kt + 2 : kt + 2 - NTS;

            short8 a[8], bf[2];
            // ---- p0: kh0, nh0
            if (alive) { ldA(a, b, 0); ldB(bf, b, 0, 0); }
            if (g1) stageA(b ^ 1, 1, xS1, k1);
            __builtin_amdgcn_s_barrier();
            __builtin_amdgcn_s_setprio(1);
            if (alive) {
                #pragma unroll
                for (int mf = 0; mf < 8; ++mf) {
                    acc[mf][0] = __builtin_amdgcn_mfma_f32_16x16x32_bf16(a[mf], bf[0], acc[mf][0], 0, 0, 0);
                    acc[mf][1] = __builtin_amdgcn_mfma_f32_16x16x32_bf16(a[mf], bf[1], acc[mf][1], 0, 0, 0);
                }
            }
            __builtin_amdgcn_s_setprio(0);
            __builtin_amdgcn_s_barrier();
            // ---- p1: kh0, nh1
            if (alive) ldB(bf, b, 0, 1);
            if (g1) stageB(b ^ 1, 1, wS1, k1);
            __builtin_amdgcn_s_barrier();
            __builtin_amdgcn_s_setprio(1);
            if (alive) {
                #pragma unroll
                for (int mf = 0; mf < 8; ++mf) {
                    acc[mf][2] = __builtin_amdgcn_mfma_f32_16x16x32_bf16(a[mf], bf[0], acc[mf][2], 0, 0, 0);
                    acc[mf][3] = __builtin_amdgcn_mfma_f32_16x16x32_bf16(a[mf], bf[1], acc[mf][3], 0, 0, 0);
                }
            }
            __builtin_amdgcn_s_setprio(0);
            if (g1) { asm volatile("s_waitcnt vmcnt(8)" ::: "memory"); }
            else    { asm volatile("s_waitcnt vmcnt(0)" ::: "memory"); }
            __builtin_amdgcn_s_barrier();
            // ---- p2: kh1, nh0
            if (alive) { ldA(a, b, 1); ldB(bf, b, 1, 0); }
            if (g2) stageA(b, 0, xS2, k2);
            __builtin_amdgcn_s_barrier();
            __builtin_amdgcn_s_setprio(1);
            if (alive) {
                #pragma unroll
                for (int mf = 0; mf < 8; ++mf) {
                    acc[mf][0] = __builtin_amdgcn_mfma_f32_16x16x32_bf16(a[mf], bf[0], acc[mf][0], 0, 0, 0);
                    acc[mf][1] = __builtin_amdgcn_mfma_f32_16x16x32_bf16(a[mf], bf[1], acc[mf][1], 0, 0, 0);
                }
            }
            __builtin_amdgcn_s_setprio(0);
            __builtin_amdgcn_s_barrier();
            // ---- p3: kh1, nh1
            if (alive) ldB(bf, b, 1, 1);
            if (g2) stageB(b, 0, wS2, k2);
            __builtin_amdgcn_s_barrier();
            __builtin_amdgcn_s_setprio(1);
            if (alive) {
                #pragma unroll
                for (int mf = 0; mf < 8; ++mf) {
                    acc[mf][2] = __builtin_amdgcn_mfma_f32_16x16x32_bf16(a[mf], bf[0], acc[mf][2], 0, 0, 0);
                    acc[mf][3] = __builtin_amdgcn_mfma_f32_16x16x32_bf16(a[mf], bf[1], acc[mf][3], 0, 0, 0);
                }
            }
            __builtin_amdgcn_s_setprio(0);
            if (g2)      { asm volatile("s_waitcnt vmcnt(8)" ::: "memory"); }
            else if (g1) { asm volatile("s_waitcnt vmcnt(4)" ::: "memory"); }
            else         { asm volatile("s_waitcnt vmcnt(0)" ::: "memory"); }
            __builtin_amdgcn_s_barrier();
        };

        #pragma unroll 1
        for (int kt = 0; kt < NTS; kt += 2) {
            tile(0, kt);
            tile(1, kt + 1);
        }

        // epilogue for this slot (overlaps the already-issued next-tile prefetch;
        // no barrier needed: next reads/stages are already ordered by the ring)
        #pragma unroll
        for (int mf = 0; mf < 8; ++mf) {
            int rbase = r0C + wr * 128 + mf * 16 + kg * 4;
            #pragma unroll
            for (int nf = 0; nf < 4; ++nf) {
                int gc = col0 + wc * 64 + nf * 16 + lr;
                #pragma unroll
                for (int j = 0; j < 4; ++j) {
                    int gr = rbase + j;
                    float v = (gr < msC) ? acc[mf][nf][j] : 0.f;
                    oC[(size_t)gr * ND + gc] = v;
                    acc[mf][nf][j] = 0.f;
                }
            }
        }

        // shift slot window
        xC = xN; wC = wN; oC = oN; msC = msN; r0C = r0N;
        if (s + 2 < nlive) {
            int v = s_live[s + 2]; int e = v >> 3, br = v & 7;
            r0N = br * BM; msN = ms[e];
            xN = xb + ((size_t)e * MAXM + r0N) * KD;
            wN = wb + ((size_t)e * ND + col0) * KD;
            oN = out + (size_t)e * MAXM * ND;
        }
    }
}

// ---------------- Fallback: round-1 fused kernel (used only if ws too small) --------
#define FBM 128
#define FBK 32
#define FTM (MAXM/FBM)
#define FTN (ND/FBM)
#define FNT (KD/FBK)
#define LSTR 40
__global__ __launch_bounds__(256, 2) void ggemm_fused(
    const float* __restrict__ x, const float* __restrict__ w,
    const int* __restrict__ ms, float* __restrict__ out)
{
    int nwg  = gridDim.x;
    int orig = blockIdx.x;
    int cpx  = nwg >> 3;
    int bid  = (orig & 7) * cpx + (orig >> 3);
    int e   = bid / (FTM * FTN);
    int rem = bid % (FTM * FTN);
    int br  = rem % FTM;
    int bc  = rem / FTM;
    int m_size = ms[e];
    int row0 = br * FBM, col0 = bc * FBM;
    float* outE = out + (size_t)e * MAXM * ND;
    int tid = threadIdx.x;

    if (row0 >= m_size) {
        f32x4 z = (f32x4){0.f, 0.f, 0.f, 0.f};
        #pragma unroll
        for (int j = 0; j < 16; ++j) {
            int i2 = tid + j * 256;
            int rr = i2 >> 5, cc = (i2 & 31) << 2;
            *(f32x4*)(outE + (size_t)(row0 + rr) * ND + col0 + cc) = z;
        }
        return;
    }

    const float* xE = x + ((size_t)e * MAXM + row0) * KD;
    const float* wE = w + ((size_t)e * ND   + col0) * KD;

    __shared__ unsigned short As[2][FBM][LSTR];
    __shared__ unsigned short Bs[2][FBM][LSTR];

    int sr  = tid >> 3;
    int sc4 = tid & 7;
    int wid = tid >> 6, lane = tid & 63;
    int wr = wid >> 1, wc = wid & 1;
    int lr = lane & 15, kg = lane >> 4;

    f32x4 acc[4][4];
    #pragma unroll
    for (int m = 0; m < 4; ++m)
        #pragma unroll
        for (int n = 0; n < 4; ++n)
            acc[m][n] = (f32x4){0.f, 0.f, 0.f, 0.f};

    {
        #pragma unroll
        for (int j = 0; j < 4; ++j) {
            int r0 = sr + j * 32;
            f32x4 av = *(const f32x4*)(xE + (size_t)r0 * KD + sc4 * 4);
            f32x4 bv = *(const f32x4*)(wE + (size_t)r0 * KD + sc4 * 4);
            us4 ah = (us4){f2bf(av[0]), f2bf(av[1]), f2bf(av[2]), f2bf(av[3])};
            us4 bh = (us4){f2bf(bv[0]), f2bf(bv[1]), f2bf(bv[2]), f2bf(bv[3])};
            *(us4*)&As[0][r0][sc4 * 4] = ah;
            *(us4*)&Bs[0][r0][sc4 * 4] = bh;
        }
    }
    __syncthreads();

    for (int t = 0; t < FNT; ++t) {
        int cur = t & 1;
        f32x4 av[4], bv[4];
        bool pre = (t + 1 < FNT);
        if (pre) {
            const float* xk = xE + (size_t)(t + 1) * FBK;
            const float* wk = wE + (size_t)(t + 1) * FBK;
            #pragma unroll
            for (int j = 0; j < 4; ++j) {
                int r0 = sr + j * 32;
                av[j] = *(const f32x4*)(xk + (size_t)r0 * KD + sc4 * 4);
                bv[j] = *(const f32x4*)(wk + (size_t)r0 * KD + sc4 * 4);
            }
        }
        short8 a[4], b[4];
        #pragma unroll
        for (int m = 0; m < 4; ++m)
            a[m] = *(const short8*)&As[cur][wr * 64 + m * 16 + lr][kg * 8];
        #pragma unroll
        for (int n = 0; n < 4; ++n)
            b[n] = *(const short8*)&Bs[cur][wc * 64 + n * 16 + lr][kg * 8];
        #pragma unroll
        for (int m = 0; m < 4; ++m)
            #pragma unroll
            for (int n = 0; n < 4; ++n)
                acc[m][n] = __builtin_amdgcn_mfma_f32_16x16x32_bf16(a[m], b[n], acc[m][n], 0, 0, 0);

        if (pre) {
            int nb = cur ^ 1;
            #pragma unroll
            for (int j = 0; j < 4; ++j) {
                int r0 = sr + j * 32;
                us4 ah = (us4){f2bf(av[j][0]), f2bf(av[j][1]), f2bf(av[j][2]), f2bf(av[j][3])};
                us4 bh = (us4){f2bf(bv[j][0]), f2bf(bv[j][1]), f2bf(bv[j][2]), f2bf(bv[j][3])};
                *(us4*)&As[nb][r0][sc4 * 4] = ah;
                *(us4*)&Bs[nb][r0][sc4 * 4] = bh;
            }
        }
        __syncthreads();
    }

    #pragma unroll
    for (int m = 0; m < 4; ++m) {
        int rbase = row0 + wr * 64 + m * 16 + kg * 4;
        #pragma unroll
        for (int n = 0; n < 4; ++n) {
            int gc = col0 + wc * 64 + n * 16 + lr;
            #pragma unroll
            for (int j = 0; j < 4; ++j) {
                int gr = rbase + j;
                float v = (gr < m_size) ? acc[m][n][j] : 0.f;
                outE[(size_t)gr * ND + gc] = v;
            }
        }
    }
}

extern "C" void kernel_launch(void* const* d_in, const int* in_sizes, int n_in,
                              void* d_out, int out_size, void* d_ws, size_t ws_size,
                              hipStream_t stream) {
    const float* x  = (const float*)d_in[0];
    const float* w  = (const float*)d_in[1];
    const int*   ms = (const int*)d_in[2];
    float* out = (float*)d_out;

    const size_t xElems = (size_t)NE * MAXM * KD;   // 33,554,432
    const size_t wElems = (size_t)NE * ND   * KD;   // 134,217,728
    const size_t need   = (xElems + wElems) * 2;    // 335,544,320 B

    if (ws_size >= need) {
        unsigned short* xb = (unsigned short*)d_ws;
        unsigned short* wb = xb + xElems;
        cvt_x_kernel<<<NE * MAXM, 256, 0, stream>>>(x, xb, ms);
        cvt_kernel<<<2048, 256, 0, stream>>>(w, wb, (int)(wElems / 8));
        ggemm_pers<<<256, 512, 0, stream>>>(xb, wb, ms, out);
    } else {
        ggemm_fused<<<dim3(NE * (MAXM/FBM) * (ND/FBM)), dim3(256), 0, stream>>>(x, w, ms, out);
    }
}

// Round 6
// 581.248 us; speedup vs baseline: 1.5246x; 1.0045x over previous
//
#include <hip/hip_runtime.h>
#include <hip/hip_bf16.h>

// BMMGroupedGEMM: out[e,m,n] = sum_k x[e,m,k] * w[e,n,k], rows m >= m_sizes[e] zeroed.
// E=8, MAX_M=2048, K=2048, N=8192. fp32 in/out.
// Round 6: (1) 2 phases per K-tile (32-MFMA clusters) -- halves barrier/gap overhead
// that round-5 analysis showed dominates (1140 cyc/phase x 4 phases vs 620 MFMA);
// (2) vmcnt(8) at both phase ends -> 2-3 phases of flight per staged region;
// (3) balanced expert-major per-XCD work list (stride-32) -> per-XCD work identical
// AND each 32-item round = one expert's 8br x 4bc supertile (L2/L3 locality).

#define NE   8
#define MAXM 2048
#define KD   2048
#define ND   8192

#define BM   256
#define BN   256
#define BK   64
#define NTS  (KD/BK)     // 32 K-tiles per output tile

typedef __attribute__((ext_vector_type(8))) short          short8;
typedef __attribute__((ext_vector_type(8))) unsigned short us8;
typedef __attribute__((ext_vector_type(4))) float          f32x4;
typedef __attribute__((ext_vector_type(4))) unsigned short us4;

__device__ __forceinline__ unsigned short f2bf(float f) {
    union { float f; unsigned u; } v; v.f = f;
    unsigned u = v.u;
    return (unsigned short)((u + 0x7FFFu + ((u >> 16) & 1u)) >> 16);  // RNE
}

__device__ __forceinline__ void gload16(const void* g, void* l) {
    __builtin_amdgcn_global_load_lds(
        (const __attribute__((address_space(1))) void*)g,
        (__attribute__((address_space(3))) void*)l, 16, 0, 0);
}

// ---------------- Pass 1a: fp32 -> bf16 for W (full) ----------------
__global__ __launch_bounds__(256) void cvt_kernel(const float* __restrict__ src,
                                                  unsigned short* __restrict__ dst,
                                                  int n8) {
    int i = blockIdx.x * blockDim.x + threadIdx.x;
    int stride = gridDim.x * blockDim.x;
    for (; i < n8; i += stride) {
        const f32x4* s = (const f32x4*)(src + (size_t)i * 8);
        f32x4 a = s[0], b = s[1];
        us8 v = (us8){f2bf(a[0]), f2bf(a[1]), f2bf(a[2]), f2bf(a[3]),
                      f2bf(b[0]), f2bf(b[1]), f2bf(b[2]), f2bf(b[3])};
        *(us8*)(dst + (size_t)i * 8) = v;
    }
}

// ---------------- Pass 1b: fp32 -> bf16 for X, masked rows skipped ----------------
// Skipped rows leave ws garbage; products land only in masked row-local outputs,
// which the epilogue overwrites with literal 0.
__global__ __launch_bounds__(256) void cvt_x_kernel(const float* __restrict__ src,
                                                    unsigned short* __restrict__ dst,
                                                    const int* __restrict__ ms) {
    int bid = blockIdx.x;            // E*MAXM rows
    int e = bid >> 11, m = bid & 2047;
    if (m >= ms[e]) return;
    const float* s = src + ((size_t)e * MAXM + m) * KD;
    unsigned short* d = dst + ((size_t)e * MAXM + m) * KD;
    int t = threadIdx.x;
    const f32x4* s4 = (const f32x4*)(s + t * 8);
    f32x4 a = s4[0], b = s4[1];
    us8 v = (us8){f2bf(a[0]), f2bf(a[1]), f2bf(a[2]), f2bf(a[3]),
                  f2bf(b[0]), f2bf(b[1]), f2bf(b[2]), f2bf(b[3])};
    *(us8*)(d + t * 8) = v;
}

// ---------------- Pass 2: persistent 2-phase/K-tile 256x256 bf16 GEMM ----------------
// LDS: A[buf][kh] 256x32 bf16 (16KB) x4 = 64KB; B same = 64KB. Total 128KB.
// Read swizzle slot = kg ^ ((row>>1)&3); write side via pre-swizzled GLOBAL source.
//
// Per K-tile t (buf b = vk&1), 2 phases:
//  P0: ldA(kh0):8 + ldB(kh0):4 | stage kh1(t+1)->[b^1][1] (4) | BAR |
//      setprio 32 MFMA | vmcnt(8) | BAR
//  P1: ldA(kh1):8 + ldB(kh1):4 | stage kh0(t+2)->[b][0]   (4) | BAR |
//      setprio 32 MFMA | vmcnt(8) | BAR
// Ledger (per-wave, 4 gload per stage-group): prologue issues kh0(t0),kh1(t0),
// kh0(t1) = 12, vmcnt(8) drains kh0(t0). Steady: entering P0(t) outstanding 8 =
// {kh1(t),kh0(t+1)}; P0 issues 4 -> 12, vmcnt(8) drains kh1(t) (read at P1(t));
// P1 issues 4 -> 12, vmcnt(8) drains kh0(t+1) (read at P0(t+1)). Every region
// has 2-3 phases of flight. Tail: guards g1/g2 -> vmcnt(0) (last 2 K-tiles only).
// Region overwrite safety: each stage-issue is after the closing barrier of the
// phase whose reads last touched that region; writes land before the drain that
// precedes the next reader.
__global__ __launch_bounds__(512, 2) void ggemm_pers(
    const unsigned short* __restrict__ xb,  // [E][MAXM][KD] bf16
    const unsigned short* __restrict__ wb,  // [E][ND][KD]  bf16
    const int*   __restrict__ ms,
    float*       __restrict__ out)          // [E][MAXM][ND] fp32
{
    int p   = blockIdx.x;          // 256 blocks, 1 per CU
    int xcd = p & 7;               // HW round-robins consecutive blockIdx over XCDs
    int jj  = p >> 3;              // 0..31 within XCD
    int tid = threadIdx.x;

    __shared__ int s_live[8], s_dead[8], s_cnt[2];
    __shared__ unsigned short Ak[2][2][BM * 32];   // 64 KB
    __shared__ unsigned short Bk[2][2][BN * 32];   // 64 KB

    // Per-XCD work list, expert-major, br-major within expert, 4 local bc columns.
    // Block jj takes items jj, jj+32, ... -> each 32-item round = one expert's
    // 8br x 4bc supertile (all XCDs in the same expert window simultaneously).
    if (tid == 0) {
        int nl = 0, nd = 0, cumL = 0, cumD = 0, il = jj, id = jj;
        #pragma unroll
        for (int e = 0; e < NE; ++e) {
            int L = (ms[e] + 255) >> 8;            // live br rows, 0..8
            int cntL = L << 2, cntD = (8 - L) << 2;
            while (il < cumL + cntL) { int o = il - cumL; s_live[nl++] = (e << 5) | ((o >> 2) << 2) | (o & 3); il += 32; }
            while (id < cumD + cntD) { int o = id - cumD; s_dead[nd++] = (e << 5) | ((L + (o >> 2)) << 2) | (o & 3); id += 32; }
            cumL += cntL; cumD += cntD;
        }
        s_cnt[0] = nl; s_cnt[1] = nd;
    }
    __syncthreads();

    // zero-fill dead tiles
    int ndead = s_cnt[1];
    #pragma unroll 1
    for (int d = 0; d < ndead; ++d) {
        int v = s_dead[d]; int e = v >> 5, br = (v >> 2) & 7, bcl = v & 3;
        float* outE = out + (size_t)e * MAXM * ND;
        int row0 = br * BM, col0 = (xcd * 4 + bcl) * BN;
        f32x4 z = (f32x4){0.f, 0.f, 0.f, 0.f};
        #pragma unroll
        for (int q = 0; q < 32; ++q) {
            int i2 = tid + q * 512;
            int rr = i2 >> 6, cc = (i2 & 63) << 2;
            *(f32x4*)(outE + (size_t)(row0 + rr) * ND + col0 + cc) = z;
        }
    }
    int nlive = s_cnt[0];
    if (nlive == 0) return;

    int wid = tid >> 6, lane = tid & 63;
    int wr = wid >> 2, wc = wid & 3;            // 2x4 wave grid; wave owns 128x64
    int lr = lane & 15, kg = lane >> 4;
    int srow = lane >> 2;
    int ss   = (lane & 3) ^ ((lane >> 3) & 3);  // pre-swizzled source slot (involution)

    auto stageA = [&](int b, int kh, const unsigned short* xP, int kt) {
        #pragma unroll
        for (int q = 0; q < 2; ++q) {
            int blk = wid * 2 + q;
            const unsigned short* src =
                xP + (size_t)(blk * 16 + srow) * KD + kt * BK + kh * 32 + ss * 8;
            gload16(src, (char*)&Ak[b][kh][0] + blk * 1024);
        }
    };
    auto stageB = [&](int b, int kh, const unsigned short* wP, int kt) {
        #pragma unroll
        for (int q = 0; q < 2; ++q) {
            int blk = wid * 2 + q;
            const unsigned short* src =
                wP + (size_t)(blk * 16 + srow) * KD + kt * BK + kh * 32 + ss * 8;
            gload16(src, (char*)&Bk[b][kh][0] + blk * 1024);
        }
    };
    auto ldA = [&](short8* a, int b, int kh) {
        #pragma unroll
        for (int mf = 0; mf < 8; ++mf) {
            int row  = wr * 128 + mf * 16 + lr;
            int slot = kg ^ ((row >> 1) & 3);
            a[mf] = *(const short8*)&Ak[b][kh][row * 32 + slot * 8];
        }
    };
    auto ldB4 = [&](short8* bf, int b, int kh) {
        #pragma unroll
        for (int i = 0; i < 4; ++i) {
            int row  = wc * 64 + i * 16 + lr;
            int slot = kg ^ ((row >> 1) & 3);
            bf[i] = *(const short8*)&Bk[b][kh][row * 32 + slot * 8];
        }
    };

    f32x4 acc[8][4];
    #pragma unroll
    for (int mf = 0; mf < 8; ++mf)
        #pragma unroll
        for (int nf = 0; nf < 4; ++nf)
            acc[mf][nf] = (f32x4){0.f, 0.f, 0.f, 0.f};

    // slot metadata (cur / next)
    const unsigned short *xC, *wC, *xN, *wN;
    float *oC, *oN;
    int msC, r0C, c0C, msN, r0N, c0N;
    {
        int v = s_live[0]; int e = v >> 5, br = (v >> 2) & 7, bcl = v & 3;
        r0C = br * BM; c0C = (xcd * 4 + bcl) * BN; msC = ms[e];
        xC = xb + ((size_t)e * MAXM + r0C) * KD;
        wC = wb + ((size_t)e * ND + c0C) * KD;
        oC = out + (size_t)e * MAXM * ND;
    }
    if (nlive > 1) {
        int v = s_live[1]; int e = v >> 5, br = (v >> 2) & 7, bcl = v & 3;
        r0N = br * BM; c0N = (xcd * 4 + bcl) * BN; msN = ms[e];
        xN = xb + ((size_t)e * MAXM + r0N) * KD;
        wN = wb + ((size_t)e * ND + c0N) * KD;
        oN = out + (size_t)e * MAXM * ND;
    } else { xN = xC; wN = wC; oN = oC; msN = msC; r0N = r0C; c0N = c0C; }

    // prologue: kh0(t0)->[0][0], kh1(t0)->[0][1], kh0(t1)->[1][0]; drain kh0(t0)
    stageA(0, 0, xC, 0); stageB(0, 0, wC, 0);
    stageA(0, 1, xC, 0); stageB(0, 1, wC, 0);
    stageA(1, 0, xC, 1); stageB(1, 0, wC, 1);
    asm volatile("s_waitcnt vmcnt(8)" ::: "memory");
    __builtin_amdgcn_s_barrier();

    #pragma unroll 1
    for (int s = 0; s < nlive; ++s) {
        bool last  = (s + 1 >= nlive);
        bool alive = (r0C + wr * 128) < msC;   // wave-uniform dead-half skip

        auto tile = [&](int b, int kt) {
            bool g1 = (kt + 1 < NTS) || (!last);
            bool g2 = (kt + 2 < NTS) || (!last);
            const unsigned short* xS1 = (kt + 1 < NTS) ? xC : xN;
            const unsigned short* wS1 = (kt + 1 < NTS) ? wC : wN;
            int k1 = (kt + 1 < NTS) ? kt + 1 : 0;
            const unsigned short* xS2 = (kt + 2 < NTS) ? xC : xN;
            const unsigned short* wS2 = (kt + 2 < NTS) ? wC : wN;
            int k2 = (kt + 2 < NTS) ? kt + 2 : kt + 2 - NTS;

            short8 a[8], bf[4];
            // ---- P0: kh0 (full K=32, all 4 nf)
            if (alive) { ldA(a, b, 0); ldB4(bf, b, 0); }
            if (g1) { stageA(b ^ 1, 1, xS1, k1); stageB(b ^ 1, 1, wS1, k1); }
            __builtin_amdgcn_s_barrier();
            __builtin_amdgcn_s_setprio(1);
            if (alive) {
                #pragma unroll
                for (int mf = 0; mf < 8; ++mf)
                    #pragma unroll
                    for (int nf = 0; nf < 4; ++nf)
                        acc[mf][nf] = __builtin_amdgcn_mfma_f32_16x16x32_bf16(a[mf], bf[nf], acc[mf][nf], 0, 0, 0);
            }
            __builtin_amdgcn_s_setprio(0);
            if (g1) { asm volatile("s_waitcnt vmcnt(8)" ::: "memory"); }
            else    { asm volatile("s_waitcnt vmcnt(0)" ::: "memory"); }
            __builtin_amdgcn_s_barrier();
            // ---- P1: kh1
            if (alive) { ldA(a, b, 1); ldB4(bf, b, 1); }
            if (g2) { stageA(b, 0, xS2, k2); stageB(b, 0, wS2, k2); }
            __builtin_amdgcn_s_barrier();
            __builtin_amdgcn_s_setprio(1);
            if (alive) {
                #pragma unroll
                for (int mf = 0; mf < 8; ++mf)
                    #pragma unroll
                    for (int nf = 0; nf < 4; ++nf)
                        acc[mf][nf] = __builtin_amdgcn_mfma_f32_16x16x32_bf16(a[mf], bf[nf], acc[mf][nf], 0, 0, 0);
            }
            __builtin_amdgcn_s_setprio(0);
            if (g2) { asm volatile("s_waitcnt vmcnt(8)" ::: "memory"); }
            else    { asm volatile("s_waitcnt vmcnt(0)" ::: "memory"); }
            __builtin_amdgcn_s_barrier();
        };

        #pragma unroll 1
        for (int kt = 0; kt < NTS; kt += 2) {
            tile(0, kt);
            tile(1, kt + 1);
        }

        // epilogue for this slot (overlaps already-issued next-slot prefetch)
        #pragma unroll
        for (int mf = 0; mf < 8; ++mf) {
            int rbase = r0C + wr * 128 + mf * 16 + kg * 4;
            #pragma unroll
            for (int nf = 0; nf < 4; ++nf) {
                int gc = c0C + wc * 64 + nf * 16 + lr;
                #pragma unroll
                for (int q = 0; q < 4; ++q) {
                    int gr = rbase + q;
                    float v = (gr < msC) ? acc[mf][nf][q] : 0.f;
                    oC[(size_t)gr * ND + gc] = v;
                    acc[mf][nf][q] = 0.f;
                }
            }
        }

        // shift slot window
        xC = xN; wC = wN; oC = oN; msC = msN; r0C = r0N; c0C = c0N;
        if (s + 2 < nlive) {
            int v = s_live[s + 2]; int e = v >> 5, br = (v >> 2) & 7, bcl = v & 3;
            r0N = br * BM; c0N = (xcd * 4 + bcl) * BN; msN = ms[e];
            xN = xb + ((size_t)e * MAXM + r0N) * KD;
            wN = wb + ((size_t)e * ND + c0N) * KD;
            oN = out + (size_t)e * MAXM * ND;
        }
    }
}

// ---------------- Fallback: round-1 fused kernel (used only if ws too small) --------
#define FBM 128
#define FBK 32
#define FTM (MAXM/FBM)
#define FTN (ND/FBM)
#define FNT (KD/FBK)
#define LSTR 40
__global__ __launch_bounds__(256, 2) void ggemm_fused(
    const float* __restrict__ x, const float* __restrict__ w,
    const int* __restrict__ ms, float* __restrict__ out)
{
    int nwg  = gridDim.x;
    int orig = blockIdx.x;
    int cpx  = nwg >> 3;
    int bid  = (orig & 7) * cpx + (orig >> 3);
    int e   = bid / (FTM * FTN);
    int rem = bid % (FTM * FTN);
    int br  = rem % FTM;
    int bc  = rem / FTM;
    int m_size = ms[e];
    int row0 = br * FBM, col0 = bc * FBM;
    float* outE = out + (size_t)e * MAXM * ND;
    int tid = threadIdx.x;

    if (row0 >= m_size) {
        f32x4 z = (f32x4){0.f, 0.f, 0.f, 0.f};
        #pragma unroll
        for (int q = 0; q < 16; ++q) {
            int i2 = tid + q * 256;
            int rr = i2 >> 5, cc = (i2 & 31) << 2;
            *(f32x4*)(outE + (size_t)(row0 + rr) * ND + col0 + cc) = z;
        }
        return;
    }

    const float* xE = x + ((size_t)e * MAXM + row0) * KD;
    const float* wE = w + ((size_t)e * ND   + col0) * KD;

    __shared__ unsigned short As[2][FBM][LSTR];
    __shared__ unsigned short Bs[2][FBM][LSTR];

    int sr  = tid >> 3;
    int sc4 = tid & 7;
    int wid = tid >> 6, lane = tid & 63;
    int wr = wid >> 1, wc = wid & 1;
    int lr = lane & 15, kg = lane >> 4;

    f32x4 acc[4][4];
    #pragma unroll
    for (int m = 0; m < 4; ++m)
        #pragma unroll
        for (int n = 0; n < 4; ++n)
            acc[m][n] = (f32x4){0.f, 0.f, 0.f, 0.f};

    {
        #pragma unroll
        for (int q = 0; q < 4; ++q) {
            int r0 = sr + q * 32;
            f32x4 av = *(const f32x4*)(xE + (size_t)r0 * KD + sc4 * 4);
            f32x4 bv = *(const f32x4*)(wE + (size_t)r0 * KD + sc4 * 4);
            us4 ah = (us4){f2bf(av[0]), f2bf(av[1]), f2bf(av[2]), f2bf(av[3])};
            us4 bh = (us4){f2bf(bv[0]), f2bf(bv[1]), f2bf(bv[2]), f2bf(bv[3])};
            *(us4*)&As[0][r0][sc4 * 4] = ah;
            *(us4*)&Bs[0][r0][sc4 * 4] = bh;
        }
    }
    __syncthreads();

    for (int t = 0; t < FNT; ++t) {
        int cur = t & 1;
        f32x4 av[4], bv[4];
        bool pre = (t + 1 < FNT);
        if (pre) {
            const float* xk = xE + (size_t)(t + 1) * FBK;
            const float* wk = wE + (size_t)(t + 1) * FBK;
            #pragma unroll
            for (int q = 0; q < 4; ++q) {
                int r0 = sr + q * 32;
                av[q] = *(const f32x4*)(xk + (size_t)r0 * KD + sc4 * 4);
                bv[q] = *(const f32x4*)(wk + (size_t)r0 * KD + sc4 * 4);
            }
        }
        short8 a[4], b[4];
        #pragma unroll
        for (int m = 0; m < 4; ++m)
            a[m] = *(const short8*)&As[cur][wr * 64 + m * 16 + lr][kg * 8];
        #pragma unroll
        for (int n = 0; n < 4; ++n)
            b[n] = *(const short8*)&Bs[cur][wc * 64 + n * 16 + lr][kg * 8];
        #pragma unroll
        for (int m = 0; m < 4; ++m)
            #pragma unroll
            for (int n = 0; n < 4; ++n)
                acc[m][n] = __builtin_amdgcn_mfma_f32_16x16x32_bf16(a[m], b[n], acc[m][n], 0, 0, 0);

        if (pre) {
            int nb = cur ^ 1;
            #pragma unroll
            for (int q = 0; q < 4; ++q) {
                int r0 = sr + q * 32;
                us4 ah = (us4){f2bf(av[q][0]), f2bf(av[q][1]), f2bf(av[q][2]), f2bf(av[q][3])};
                us4 bh = (us4){f2bf(bv[q][0]), f2bf(bv[q][1]), f2bf(bv[q][2]), f2bf(bv[q][3])};
                *(us4*)&As[nb][r0][sc4 * 4] = ah;
                *(us4*)&Bs[nb][r0][sc4 * 4] = bh;
            }
        }
        __syncthreads();
    }

    #pragma unroll
    for (int m = 0; m < 4; ++m) {
        int rbase = row0 + wr * 64 + m * 16 + kg * 4;
        #pragma unroll
        for (int n = 0; n < 4; ++n) {
            int gc = col0 + wc * 64 + n * 16 + lr;
            #pragma unroll
            for (int q = 0; q < 4; ++q) {
                int gr = rbase + q;
                float v = (gr < m_size) ? acc[m][n][q] : 0.f;
                outE[(size_t)gr * ND + gc] = v;
            }
        }
    }
}

extern "C" void kernel_launch(void* const* d_in, const int* in_sizes, int n_in,
                              void* d_out, int out_size, void* d_ws, size_t ws_size,
                              hipStream_t stream) {
    const float* x  = (const float*)d_in[0];
    const float* w  = (const float*)d_in[1];
    const int*   ms = (const int*)d_in[2];
    float* out = (float*)d_out;

    const size_t xElems = (size_t)NE * MAXM * KD;   // 33,554,432
    const size_t wElems = (size_t)NE * ND   * KD;   // 134,217,728
    const size_t need   = (xElems + wElems) * 2;    // 335,544,320 B

    if (ws_size >= need) {
        unsigned short* xb = (unsigned short*)d_ws;
        unsigned short* wb = xb + xElems;
        cvt_x_kernel<<<NE * MAXM, 256, 0, stream>>>(x, xb, ms);
        cvt_kernel<<<2048, 256, 0, stream>>>(w, wb, (int)(wElems / 8));
        ggemm_pers<<<256, 512, 0, stream>>>(xb, wb, ms, out);
    } else {
        ggemm_fused<<<dim3(NE * (MAXM/FBM) * (ND/FBM)), dim3(256), 0, stream>>>(x, w, ms, out);
    }
}